// Round 9
// baseline (763.876 us; speedup 1.0000x reference)
//
#include <hip/hip_runtime.h>

typedef unsigned short u16;
typedef unsigned int u32;
typedef __attribute__((ext_vector_type(8))) __bf16 bf16x8;
typedef __attribute__((ext_vector_type(4))) float f32x4;
typedef __attribute__((ext_vector_type(4))) u32 u32x4;
typedef __attribute__((ext_vector_type(8))) u16 u16x8;
typedef __attribute__((ext_vector_type(4))) u16 u16x4;

#define S_LEN 2048
#define DM 3072
#define NH 24
#define NKV 8

__device__ __forceinline__ u16 f2b(float f) {
  u32 u = __builtin_bit_cast(u32, f);
  u = u + 0x7FFFu + ((u >> 16) & 1u);
  return (u16)(u >> 16);
}
__device__ __forceinline__ float b2f(u16 h) {
  u32 u = ((u32)h) << 16;
  return __builtin_bit_cast(float, u);
}
__device__ __forceinline__ u32 cvtpk(float lo, float hi) {
  u32 r;
  asm("v_cvt_pk_bf16_f32 %0, %1, %2" : "=v"(r) : "v"(lo), "v"(hi));
  return r;
}
__device__ __forceinline__ f32x4 mfma16(bf16x8 a, bf16x8 b, f32x4 c) {
  return __builtin_amdgcn_mfma_f32_16x16x32_bf16(a, b, c, 0, 0, 0);
}
__device__ __forceinline__ void gload16(const u16* g, u16* l) {
  __builtin_amdgcn_global_load_lds((const __attribute__((address_space(1))) void*)g,
                                   (__attribute__((address_space(3))) void*)l, 16, 0, 0);
}

// ---------------- f32 -> bf16 conversion ----------------
__device__ __forceinline__ void cvt_one(const float* __restrict__ s, u16* __restrict__ d, int j) {
  const f32x4* p = (const f32x4*)(s + (size_t)j * 8);
  f32x4 a = p[0], b = p[1];
  u16x8 o;
#pragma unroll
  for (int q = 0; q < 4; ++q) { o[q] = f2b(a[q]); o[q + 4] = f2b(b[q]); }
  *(u16x8*)(d + (size_t)j * 8) = o;
}
__global__ __launch_bounds__(256) void cvt_kernel(const float* __restrict__ s,
                                                  u16* __restrict__ d, int n8) {
  int i = blockIdx.x * 256 + threadIdx.x;
  if (i >= n8) return;
  cvt_one(s, d, i);
}
__global__ __launch_bounds__(256) void cvt4_kernel(const float* __restrict__ s0, u16* __restrict__ d0,
                                                   const float* __restrict__ s1, u16* __restrict__ d1,
                                                   const float* __restrict__ s2, u16* __restrict__ d2,
                                                   const float* __restrict__ s3, u16* __restrict__ d3) {
  int i = blockIdx.x * 256 + threadIdx.x;
  if (i < 1572864)      cvt_one(s0, d0, i);
  else if (i < 2752512) cvt_one(s1, d1, i - 1572864);
  else if (i < 3145728) cvt_one(s2, d2, i - 2752512);
  else                  cvt_one(s3, d3, i - 3145728);
}

// ---------------- XCD-aware block swizzle ----------------
__device__ __forceinline__ void swz_bid(int& bx, int& by) {
  int gx = gridDim.x;
  int tot = gx * gridDim.y;          // must be divisible by 8
  int id = blockIdx.y * gx + blockIdx.x;
  int cpx = tot >> 3;
  int s = (id & 7) * cpx + (id >> 3);
  bx = s % gx;
  by = s / gx;
}

// ---------------- 256-wide phase-interleaved GEMM (unchanged from r8) ----------------
template <int BN>
__device__ __forceinline__ void gemm256_body(const u16* __restrict__ A, const u16* __restrict__ B,
                                             void* __restrict__ Cv, int N, int K,
                                             int m0, int n0, int mode) {
  constexpr int NJ = BN / 64;
  constexpr int BHALF = BN / 128;
  constexpr int BBUF = BN * 64;
  __shared__ __align__(16) u16 lds[32768 + 2 * BBUF];
  const int tid = threadIdx.x;
  const int lane = tid & 63;
  const int w = tid >> 6;
  const int l15 = lane & 15, g = lane >> 4;
  const int wm = w >> 2, wn = w & 3;
  const int srow = tid >> 3;
  const int scol = ((tid & 7) ^ (srow & 7)) * 8;
  const u16* aS = A + (size_t)(m0 + srow) * K + scol;
  const u16* bS = B + (size_t)(n0 + srow) * K + scol;
  const int sdst = (tid & 448) * 8;
  const int swz0 = (g ^ (l15 & 7)) * 8;
  const int swz1 = ((4 + g) ^ (l15 & 7)) * 8;
  const int aB0 = wm * 8192 + l15 * 64;
  const int bB0 = (BN == 256 ? ((wn >> 1) * 8192 + (wn & 1) * 4096) : wn * 2048) + l15 * 64;

  f32x4 acc[8][NJ];
#pragma unroll
  for (int i = 0; i < 8; ++i)
#pragma unroll
    for (int j = 0; j < NJ; ++j) acc[i][j] = 0.f;

  auto stage = [&](int k0, int bsel) {
#pragma unroll
    for (int h = 0; h < 2; ++h)
#pragma unroll
      for (int j = 0; j < 2; ++j)
        gload16(aS + (size_t)(h * 128 + j * 64) * K + k0,
                lds + bsel * 16384 + h * 8192 + j * 4096 + sdst);
#pragma unroll
    for (int h = 0; h < BHALF; ++h)
#pragma unroll
      for (int j = 0; j < 2; ++j)
        gload16(bS + (size_t)(h * 128 + j * 64) * K + k0,
                lds + 32768 + bsel * BBUF + h * 8192 + j * 4096 + sdst);
  };

  stage(0, 0);
  asm volatile("s_waitcnt vmcnt(0)" ::: "memory");
  __builtin_amdgcn_s_barrier();

  for (int t = 0; t < 48; ++t) {
    const int bsel = t & 1;
    const u16* ldsA = lds + bsel * 16384 + aB0;
    const u16* ldsB = lds + 32768 + bsel * BBUF + bB0;
    bf16x8 af[4], bf[NJ];
    // ---- P0
#pragma unroll
    for (int i = 0; i < 4; ++i) af[i] = *(const bf16x8*)(ldsA + i * 1024 + swz0);
#pragma unroll
    for (int j = 0; j < NJ; ++j) bf[j] = *(const bf16x8*)(ldsB + j * 1024 + swz0);
    if (t < 47) stage((t + 1) * 64, bsel ^ 1);
    asm volatile("" ::: "memory");
    __builtin_amdgcn_s_barrier();
    asm volatile("s_waitcnt lgkmcnt(0)" ::: "memory");
    __builtin_amdgcn_sched_barrier(0);
    __builtin_amdgcn_s_setprio(1);
#pragma unroll
    for (int i = 0; i < 4; ++i)
#pragma unroll
      for (int j = 0; j < NJ; ++j) acc[i][j] = mfma16(af[i], bf[j], acc[i][j]);
    __builtin_amdgcn_s_setprio(0);
    asm volatile("" ::: "memory");
    __builtin_amdgcn_s_barrier();
    // ---- P1
#pragma unroll
    for (int i = 0; i < 4; ++i) af[i] = *(const bf16x8*)(ldsA + (4 + i) * 1024 + swz0);
    asm volatile("" ::: "memory");
    __builtin_amdgcn_s_barrier();
    asm volatile("s_waitcnt lgkmcnt(0)" ::: "memory");
    __builtin_amdgcn_sched_barrier(0);
    __builtin_amdgcn_s_setprio(1);
#pragma unroll
    for (int i = 0; i < 4; ++i)
#pragma unroll
      for (int j = 0; j < NJ; ++j) acc[4 + i][j] = mfma16(af[i], bf[j], acc[4 + i][j]);
    __builtin_amdgcn_s_setprio(0);
    asm volatile("" ::: "memory");
    __builtin_amdgcn_s_barrier();
    // ---- P2
#pragma unroll
    for (int i = 0; i < 4; ++i) af[i] = *(const bf16x8*)(ldsA + i * 1024 + swz1);
#pragma unroll
    for (int j = 0; j < NJ; ++j) bf[j] = *(const bf16x8*)(ldsB + j * 1024 + swz1);
    asm volatile("" ::: "memory");
    __builtin_amdgcn_s_barrier();
    asm volatile("s_waitcnt lgkmcnt(0)" ::: "memory");
    __builtin_amdgcn_sched_barrier(0);
    __builtin_amdgcn_s_setprio(1);
#pragma unroll
    for (int i = 0; i < 4; ++i)
#pragma unroll
      for (int j = 0; j < NJ; ++j) acc[i][j] = mfma16(af[i], bf[j], acc[i][j]);
    __builtin_amdgcn_s_setprio(0);
    asm volatile("" ::: "memory");
    __builtin_amdgcn_s_barrier();
    // ---- P3
#pragma unroll
    for (int i = 0; i < 4; ++i) af[i] = *(const bf16x8*)(ldsA + (4 + i) * 1024 + swz1);
    asm volatile("" ::: "memory");
    asm volatile("s_waitcnt vmcnt(0)" ::: "memory");
    __builtin_amdgcn_s_barrier();
    asm volatile("s_waitcnt lgkmcnt(0)" ::: "memory");
    __builtin_amdgcn_sched_barrier(0);
    __builtin_amdgcn_s_setprio(1);
#pragma unroll
    for (int i = 0; i < 4; ++i)
#pragma unroll
      for (int j = 0; j < NJ; ++j) acc[4 + i][j] = mfma16(af[i], bf[j], acc[4 + i][j]);
    __builtin_amdgcn_s_setprio(0);
    asm volatile("" ::: "memory");
    __builtin_amdgcn_s_barrier();
  }
  // ---- epilogue
#pragma unroll
  for (int i = 0; i < 8; ++i)
#pragma unroll
    for (int j = 0; j < NJ; ++j) {
      int nn = n0 + wn * (BN / 4) + j * 16 + l15;
      int mmb = m0 + wm * 128 + i * 16 + g * 4;
      if (mode == 1) {
#pragma unroll
        for (int r = 0; r < 4; ++r)
          ((float*)Cv)[(size_t)(mmb + r) * N + nn] = acc[i][j][r];
      } else if (mode == 0) {
#pragma unroll
        for (int r = 0; r < 4; ++r)
          ((u16*)Cv)[(size_t)(mmb + r) * N + nn] = f2b(acc[i][j][r]);
      } else {
        u16x4 pk;
#pragma unroll
        for (int r = 0; r < 4; ++r) pk[r] = f2b(acc[i][j][r]);
        *(u16x4*)((u16*)Cv + (size_t)nn * 2048 + (size_t)(mmb >> 11) * 2097152 + (mmb & 2047)) = pk;
      }
    }
}

__global__ __launch_bounds__(512, 1) void gemm256_bf16(const u16* __restrict__ A, const u16* __restrict__ B,
                                                       u16* __restrict__ C, int N, int K) {
  int bx, by; swz_bid(bx, by);
  gemm256_body<256>(A, B, C, N, K, by * 256, bx * 256, 0);
}
__global__ __launch_bounds__(512, 1) void gemm256_f32(const u16* __restrict__ A, const u16* __restrict__ B,
                                                      float* __restrict__ C, int N, int K) {
  int bx, by; swz_bid(bx, by);
  gemm256_body<256>(A, B, C, N, K, by * 256, bx * 256, 1);
}
__global__ __launch_bounds__(512, 1) void gemm128_kv(const u16* __restrict__ A,
                                                     const u16* __restrict__ Bk, const u16* __restrict__ Bv,
                                                     u16* __restrict__ Ck, u16* __restrict__ Cv,
                                                     int K) {
  int bx, by; swz_bid(bx, by);
  bool isv = bx >= 8;
  gemm256_body<128>(A, isv ? Bv : Bk, isv ? Cv : Ck, 1024, K, by * 256, (bx & 7) * 128,
                    isv ? 2 : 0);
}

// ---------------- RoPE (in place, bf16) — K only ----------------
__global__ __launch_bounds__(256) void rope_kernel(u16* __restrict__ t, const float* __restrict__ fc,
                                                   const float* __restrict__ fs, int nheads, int total) {
  int idx = blockIdx.x * 256 + threadIdx.x;
  if (idx >= total) return;
  int c = idx & 7;
  int tmp = idx >> 3;
  int h = tmp % nheads;
  int row = tmp / nheads;
  int s = row & (S_LEN - 1);
  int d0 = c << 3;
  u16* base = t + (size_t)row * (nheads * 128) + h * 128;
  u16x8 lo = *(const u16x8*)(base + d0);
  u16x8 hi = *(const u16x8*)(base + 64 + d0);
  const float* cp = fc + s * 64 + d0;
  const float* sp = fs + s * 64 + d0;
  u16x8 olo, ohi;
#pragma unroll
  for (int j = 0; j < 8; ++j) {
    float cv = cp[j], sn = sp[j];
    float a = b2f(lo[j]), b = b2f(hi[j]);
    olo[j] = f2b(a * cv - b * sn);
    ohi[j] = f2b(b * cv + a * sn);
  }
  *(u16x8*)(base + d0) = olo;
  *(u16x8*)(base + 64 + d0) = ohi;
}

// ---------------- causal GQA flash attention — DIRECT K/V reads ----------------
// r8 proved K+V is L2-resident per-XCD (FETCH 86->31 MB); a CU's K-tile (16 KB)
// + V-tile (16 KB) fit L1. So: no LDS staging, no barriers at all. Each wave
// streams K/V fragments directly from global (b128, ping-pong prefetch groups),
// P through wave-local XOR-swizzled LDS (r3-proven), epilogue wave-local.
// grid: flat 384 blocks, XCD-group-pinned as in r8. LDS 32 KB -> 2+ blocks/CU.
__global__ __launch_bounds__(512, 4) void attn_kernel(const u16* __restrict__ xq,
                                                      const u16* __restrict__ xk,
                                                      const u16* __restrict__ xvT,
                                                      const float* __restrict__ fc,
                                                      const float* __restrict__ fs,
                                                      u16* __restrict__ o) {
  __shared__ __align__(16) u16 smem[16384];    // 32 KB: per-wave 2048 u16 (sP in low 1024)
  const int tid = threadIdx.x;
  const int w = tid >> 6, lane = tid & 63;
  const int l15 = lane & 15, g = lane >> 4;
  const int id = blockIdx.x;
  const int xcd = id & 7, slot = id >> 3;
  const int grp = xcd + 8 * (slot / 24);       // (b,kvh) group, 0..15
  const int jj = slot % 24;
  const int b = grp >> 3, kvh = grp & 7;
  const int h = kvh * 3 + jj % 3;
  const int bxx = jj / 3;                      // 0..7 (panel pair selector)
  const float sc2 = 0.08838834764831845f * 1.4426950408889634f;  // 1/sqrt(128)*log2e

  const u16* ksrc = xk + (size_t)b * 2097152 + kvh * 128;          // [s][1024]
  const u16* vsrc = xvT + (size_t)(b * 1024 + kvh * 128) * 2048;   // [d][2048]
  u16* sW = smem + w * 2048;                   // wave-local region; sP = sW[0..1023]
  const int pwr = (l15 * 64) ;                 // P row base
  const int pxr = (l15 & 7) << 3;              // P XOR bits

  for (int panel = 0; panel < 2; ++panel) {
    const int qb = panel == 0 ? (15 - bxx) : bxx;
    const int q0 = qb * 128;
    const int qrow = q0 + w * 16 + l15;
    const u16* qptr = xq + (size_t)(b * S_LEN + qrow) * DM + h * 128;

    // Q load + fused RoPE + pre-scale
    bf16x8 qf[4];
#pragma unroll
    for (int dcp = 0; dcp < 2; ++dcp) {
      u16x8 Lo = *(const u16x8*)(qptr + dcp * 32 + g * 8);
      u16x8 Hi = *(const u16x8*)(qptr + 64 + dcp * 32 + g * 8);
      const float* cp = fc + qrow * 64 + dcp * 32 + g * 8;
      const float* sp = fs + qrow * 64 + dcp * 32 + g * 8;
      bf16x8 qlo, qhi;
#pragma unroll
      for (int j = 0; j < 8; ++j) {
        float cv = cp[j], sn = sp[j];
        float a = b2f(Lo[j]), bb = b2f(Hi[j]);
        qlo[j] = (__bf16)((a * cv - bb * sn) * sc2);
        qhi[j] = (__bf16)((bb * cv + a * sn) * sc2);
      }
      qf[dcp] = qlo;
      qf[dcp + 2] = qhi;
    }

    f32x4 accO[8];
#pragma unroll
    for (int i = 0; i < 8; ++i) accO[i] = 0.f;
    float m = -1e30f, lsum = 0.f;
    const int nt_w = 2 * qb + 1 + (w >> 2);    // this wave's causal tile count

    for (int t = 0; t < nt_w; ++t) {
      const int k0 = t * 64;
      const u16* kT = ksrc + (size_t)k0 * 1024 + l15 * 1024 + g * 8;  // row l15, col g*8
      const u16* vT = vsrc + (size_t)l15 * 2048 + k0 + g * 8;
      // ---- QK^T: S^T[k][q], k-row = kt*16+l15, direct b128 K reads, ping-pong
      f32x4 st[4];
      bf16x8 ka[4], kb[4];
#pragma unroll
      for (int dc = 0; dc < 4; ++dc) ka[dc] = *(const bf16x8*)(kT + dc * 32);
#pragma unroll
      for (int kt = 0; kt < 4; ++kt) {
        bf16x8* cur = (kt & 1) ? kb : ka;
        bf16x8* nxt = (kt & 1) ? ka : kb;
        if (kt < 3) {
#pragma unroll
          for (int dc = 0; dc < 4; ++dc)
            nxt[dc] = *(const bf16x8*)(kT + (kt + 1) * 16384 + dc * 32);
        }
        f32x4 a = 0.f;
        __builtin_amdgcn_s_setprio(1);
#pragma unroll
        for (int dc = 0; dc < 4; ++dc) a = mfma16(cur[dc], qf[dc], a);
        __builtin_amdgcn_s_setprio(0);
        st[kt] = a;
      }
      // ---- causal mask (last two tiles) + online softmax
      float sv[4][4];
      float pmax = -1e30f;
      const bool masked = (k0 + 64 > qrow - 15);   // tile may cross the diagonal for this wave's rows
#pragma unroll
      for (int kt = 0; kt < 4; ++kt)
#pragma unroll
        for (int r = 0; r < 4; ++r) {
          float x = st[kt][r];
          if (masked) {
            int kk = k0 + kt * 16 + g * 4 + r;
            if (kk > qrow) x = -1e30f;
          }
          sv[kt][r] = x;
          pmax = fmaxf(pmax, x);
        }
      pmax = fmaxf(pmax, __shfl_xor(pmax, 16));
      pmax = fmaxf(pmax, __shfl_xor(pmax, 32));
      if (!__all(pmax - m <= 8.0f)) {          // defer-max
        float mnew = fmaxf(m, pmax);
        float corr = exp2f(m - mnew);
        lsum *= corr;
#pragma unroll
        for (int i = 0; i < 8; ++i) accO[i] *= corr;
        m = mnew;
      }
      float ps = 0.f;
#pragma unroll
      for (int kt = 0; kt < 4; ++kt) {
        u16x4 pk;
#pragma unroll
        for (int r = 0; r < 4; ++r) {
          float p = exp2f(sv[kt][r] - m);
          ps += p;
          pk[r] = f2b(p);
        }
        *(u16x4*)(sW + ((pwr + kt * 16 + g * 4) ^ pxr)) = pk;
      }
      ps += __shfl_xor(ps, 16);
      ps += __shfl_xor(ps, 32);
      lsum += ps;
      // ---- P fragments from wave-local LDS
      bf16x8 pf[2];
#pragma unroll
      for (int ck = 0; ck < 2; ++ck)
        pf[ck] = *(const bf16x8*)(sW + ((pwr + ck * 32 + g * 8) ^ pxr));
      // ---- PV: O^T[d][q] += V^T[d][k] * P[k][q], direct b128 V reads, ping-pong
      bf16x8 va[4], vb[4];
#pragma unroll
      for (int i = 0; i < 4; ++i) {
        int dt = i >> 1, ck = i & 1;
        va[i] = *(const bf16x8*)(vT + dt * 32768 + ck * 32);
      }
#pragma unroll
      for (int dp = 0; dp < 4; ++dp) {          // dt pairs: (2dp, 2dp+1) handled as 4 frags
        bf16x8* cur = (dp & 1) ? vb : va;
        bf16x8* nxt = (dp & 1) ? va : vb;
        if (dp < 3) {
#pragma unroll
          for (int i = 0; i < 4; ++i) {
            int dt = (dp + 1) * 2 + (i >> 1), ck = i & 1;
            nxt[i] = *(const bf16x8*)(vT + dt * 32768 + ck * 32);
          }
        }
        __builtin_amdgcn_s_setprio(1);
#pragma unroll
        for (int i = 0; i < 4; ++i) {
          int dt = dp * 2 + (i >> 1), ck = i & 1;
          accO[dt] = mfma16(cur[i], pf[ck], accO[dt]);
        }
        __builtin_amdgcn_s_setprio(0);
      }
    }
    // ---- epilogue: normalize, wave-local LDS transpose, coalesced writes
    float invl = 1.0f / lsum;
#pragma unroll
    for (int dt = 0; dt < 8; ++dt)
#pragma unroll
      for (int r = 0; r < 4; ++r) {
        int d = dt * 16 + g * 4 + r;
        sW[(l15 * 128 + d) ^ ((l15 & 7) << 3)] = f2b(accO[dt][r] * invl);
      }
#pragma unroll
    for (int p = 0; p < 4; ++p) {
      int idx = p * 64 + lane;
      int q = idx >> 4, d0 = (idx & 15) << 3;
      u32x4 v = *(const u32x4*)(sW + ((q * 128 + d0) ^ ((q & 7) << 3)));
      *(u32x4*)(o + (size_t)(b * S_LEN + q0 + w * 16 + q) * DM + h * 128 + d0) = v;
    }
  }
}

// ---------------- launch ----------------
extern "C" void kernel_launch(void* const* d_in, const int* in_sizes, int n_in,
                              void* d_out, int out_size, void* d_ws, size_t ws_size,
                              hipStream_t stream) {
  const float* x  = (const float*)d_in[0];
  const float* fc = (const float*)d_in[1];
  const float* fs = (const float*)d_in[2];
  const float* wq = (const float*)d_in[4];
  const float* wk = (const float*)d_in[5];
  const float* wv = (const float*)d_in[6];
  const float* wo = (const float*)d_in[7];
  float* out = (float*)d_out;
  char* ws = (char*)d_ws;

  u16* xb  = (u16*)(ws);                 // x bf16      25,165,824
  u16* wqb = (u16*)(ws + 25165824);      // wq bf16     18,874,368
  u16* att = (u16*)(ws + 25165824);      // attn out (aliases wq/wk after death)
  u16* wkb = (u16*)(ws + 44040192);      // wk bf16      6,291,456
  u16* wvb = (u16*)(ws + 50331648);      // wv bf16      6,291,456
  u16* xqb = (u16*)(ws + 56623104);      // xq bf16     25,165,824
  u16* xkb = (u16*)(ws + 81788928);      // xk bf16      8,388,608
  u16* xvT = (u16*)(ws + 90177536);      // V^T bf16     8,388,608
  u16* wob = (u16*)(ws);                 // wo bf16 (aliases xb after death)

  cvt4_kernel<<<13824, 256, 0, stream>>>(x, xb, wq, wqb, wk, wkb, wv, wvb);

  gemm256_bf16<<<dim3(12, 16), 512, 0, stream>>>(xb, wqb, xqb, 3072, 3072);
  gemm128_kv<<<dim3(16, 16), 512, 0, stream>>>(xb, wkb, wvb, xkb, xvT, 3072);

  cvt_kernel<<<4608, 256, 0, stream>>>(wo, wob, 1179648);   // after gemm_kv (aliases xb)
  rope_kernel<<<1024, 256, 0, stream>>>(xkb, fc, fs, NKV, 4096 * NKV * 8);  // K only

  attn_kernel<<<dim3(384, 1, 1), 512, 0, stream>>>(xqb, xkb, xvT, fc, fs, att);

  gemm256_f32<<<dim3(12, 16), 512, 0, stream>>>(att, wob, out, 3072, 3072);
}

// Round 10
// 410.140 us; speedup vs baseline: 1.8625x; 1.8625x over previous
//
#include <hip/hip_runtime.h>

typedef unsigned short u16;
typedef unsigned int u32;
typedef __attribute__((ext_vector_type(8))) __bf16 bf16x8;
typedef __attribute__((ext_vector_type(4))) float f32x4;
typedef __attribute__((ext_vector_type(4))) u32 u32x4;
typedef __attribute__((ext_vector_type(8))) u16 u16x8;
typedef __attribute__((ext_vector_type(4))) u16 u16x4;

#define S_LEN 2048
#define DM 3072
#define NH 24
#define NKV 8

__device__ __forceinline__ u16 f2b(float f) {
  u32 u = __builtin_bit_cast(u32, f);
  u = u + 0x7FFFu + ((u >> 16) & 1u);
  return (u16)(u >> 16);
}
__device__ __forceinline__ float b2f(u16 h) {
  u32 u = ((u32)h) << 16;
  return __builtin_bit_cast(float, u);
}
__device__ __forceinline__ u32 cvtpk(float lo, float hi) {
  u32 r;
  asm("v_cvt_pk_bf16_f32 %0, %1, %2" : "=v"(r) : "v"(lo), "v"(hi));
  return r;
}
__device__ __forceinline__ f32x4 mfma16(bf16x8 a, bf16x8 b, f32x4 c) {
  return __builtin_amdgcn_mfma_f32_16x16x32_bf16(a, b, c, 0, 0, 0);
}
__device__ __forceinline__ void gload16(const u16* g, u16* l) {
  __builtin_amdgcn_global_load_lds((const __attribute__((address_space(1))) void*)g,
                                   (__attribute__((address_space(3))) void*)l, 16, 0, 0);
}

// ---------------- f32 -> bf16 conversion ----------------
__device__ __forceinline__ void cvt_one(const float* __restrict__ s, u16* __restrict__ d, int j) {
  const f32x4* p = (const f32x4*)(s + (size_t)j * 8);
  f32x4 a = p[0], b = p[1];
  u16x8 o;
#pragma unroll
  for (int q = 0; q < 4; ++q) { o[q] = f2b(a[q]); o[q + 4] = f2b(b[q]); }
  *(u16x8*)(d + (size_t)j * 8) = o;
}
__global__ __launch_bounds__(256) void cvt_kernel(const float* __restrict__ s,
                                                  u16* __restrict__ d, int n8) {
  int i = blockIdx.x * 256 + threadIdx.x;
  if (i >= n8) return;
  cvt_one(s, d, i);
}
__global__ __launch_bounds__(256) void cvt4_kernel(const float* __restrict__ s0, u16* __restrict__ d0,
                                                   const float* __restrict__ s1, u16* __restrict__ d1,
                                                   const float* __restrict__ s2, u16* __restrict__ d2,
                                                   const float* __restrict__ s3, u16* __restrict__ d3) {
  int i = blockIdx.x * 256 + threadIdx.x;
  if (i < 1572864)      cvt_one(s0, d0, i);
  else if (i < 2752512) cvt_one(s1, d1, i - 1572864);
  else if (i < 3145728) cvt_one(s2, d2, i - 2752512);
  else                  cvt_one(s3, d3, i - 3145728);
}

// ---------------- XCD-aware block swizzle ----------------
__device__ __forceinline__ void swz_bid(int& bx, int& by) {
  int gx = gridDim.x;
  int tot = gx * gridDim.y;          // must be divisible by 8
  int id = blockIdx.y * gx + blockIdx.x;
  int cpx = tot >> 3;
  int s = (id & 7) * cpx + (id >> 3);
  bx = s % gx;
  by = s / gx;
}

// ---------------- phase-interleaved GEMM, BM=256, BN in {192,128} ----------------
// C[m,n] = sum_k A[m,k]*B[n,k], row-major over K (K=3072, 48 K-tiles of 64).
// 512 threads = 8 waves (2M x 4N); per-wave out 128 x BN/4. LDS rows linear
// (row r at r*64 u16), chunk^(row&7) swizzle, pre-swizzled global sources.
// 4 phases/K-tile, 2 barriers/phase. modes: 0 bf16, 1 f32, 2 V^T bf16.
template <int BN>
__device__ __forceinline__ void gemm256_body(const u16* __restrict__ A, const u16* __restrict__ B,
                                             void* __restrict__ Cv, int N, int K,
                                             int m0, int n0, int mode) {
  constexpr int NJ = BN / 64;                  // per-wave 16-col frags (3 or 2)
  constexpr int NSB = BN / 64;                 // B 64-row sub-blocks per buffer
  constexpr int BBUF = NSB * 4096;             // B u16 per buffer
  __shared__ __align__(16) u16 lds[32768 + 2 * BBUF];
  const int tid = threadIdx.x;
  const int lane = tid & 63;
  const int w = tid >> 6;
  const int l15 = lane & 15, g = lane >> 4;
  const int wm = w >> 2, wn = w & 3;
  const int srow = tid >> 3;
  const int scol = ((tid & 7) ^ (srow & 7)) * 8;
  const u16* aS = A + (size_t)(m0 + srow) * K + scol;
  const u16* bS = B + (size_t)(n0 + srow) * K + scol;
  const int sdst = (tid & 448) * 8;
  const int swz0 = (g ^ (l15 & 7)) * 8;
  const int swz1 = ((4 + g) ^ (l15 & 7)) * 8;
  const int aB0 = wm * 8192 + l15 * 64;
  const int bB0 = wn * (BN / 4) * 64 + l15 * 64;

  f32x4 acc[8][NJ];
#pragma unroll
  for (int i = 0; i < 8; ++i)
#pragma unroll
    for (int j = 0; j < NJ; ++j) acc[i][j] = 0.f;

  auto stage = [&](int k0, int bsel) {
#pragma unroll
    for (int s = 0; s < 4; ++s)
      gload16(aS + (size_t)(s * 64) * K + k0, lds + bsel * 16384 + s * 4096 + sdst);
#pragma unroll
    for (int s = 0; s < NSB; ++s)
      gload16(bS + (size_t)(s * 64) * K + k0, lds + 32768 + bsel * BBUF + s * 4096 + sdst);
  };

  stage(0, 0);
  asm volatile("s_waitcnt vmcnt(0)" ::: "memory");
  __builtin_amdgcn_s_barrier();

  for (int t = 0; t < 48; ++t) {
    const int bsel = t & 1;
    const u16* ldsA = lds + bsel * 16384 + aB0;
    const u16* ldsB = lds + 32768 + bsel * BBUF + bB0;
    bf16x8 af[4], bf[NJ];
    // ---- P0: kh0, mi 0-3 (+ stage next tile)
#pragma unroll
    for (int i = 0; i < 4; ++i) af[i] = *(const bf16x8*)(ldsA + i * 1024 + swz0);
#pragma unroll
    for (int j = 0; j < NJ; ++j) bf[j] = *(const bf16x8*)(ldsB + j * 1024 + swz0);
    if (t < 47) stage((t + 1) * 64, bsel ^ 1);
    asm volatile("" ::: "memory");
    __builtin_amdgcn_s_barrier();
    asm volatile("s_waitcnt lgkmcnt(0)" ::: "memory");
    __builtin_amdgcn_sched_barrier(0);
    __builtin_amdgcn_s_setprio(1);
#pragma unroll
    for (int i = 0; i < 4; ++i)
#pragma unroll
      for (int j = 0; j < NJ; ++j) acc[i][j] = mfma16(af[i], bf[j], acc[i][j]);
    __builtin_amdgcn_s_setprio(0);
    asm volatile("" ::: "memory");
    __builtin_amdgcn_s_barrier();
    // ---- P1: kh0, mi 4-7
#pragma unroll
    for (int i = 0; i < 4; ++i) af[i] = *(const bf16x8*)(ldsA + (4 + i) * 1024 + swz0);
    asm volatile("" ::: "memory");
    __builtin_amdgcn_s_barrier();
    asm volatile("s_waitcnt lgkmcnt(0)" ::: "memory");
    __builtin_amdgcn_sched_barrier(0);
    __builtin_amdgcn_s_setprio(1);
#pragma unroll
    for (int i = 0; i < 4; ++i)
#pragma unroll
      for (int j = 0; j < NJ; ++j) acc[4 + i][j] = mfma16(af[i], bf[j], acc[4 + i][j]);
    __builtin_amdgcn_s_setprio(0);
    asm volatile("" ::: "memory");
    __builtin_amdgcn_s_barrier();
    // ---- P2: kh1, mi 0-3
#pragma unroll
    for (int i = 0; i < 4; ++i) af[i] = *(const bf16x8*)(ldsA + i * 1024 + swz1);
#pragma unroll
    for (int j = 0; j < NJ; ++j) bf[j] = *(const bf16x8*)(ldsB + j * 1024 + swz1);
    asm volatile("" ::: "memory");
    __builtin_amdgcn_s_barrier();
    asm volatile("s_waitcnt lgkmcnt(0)" ::: "memory");
    __builtin_amdgcn_sched_barrier(0);
    __builtin_amdgcn_s_setprio(1);
#pragma unroll
    for (int i = 0; i < 4; ++i)
#pragma unroll
      for (int j = 0; j < NJ; ++j) acc[i][j] = mfma16(af[i], bf[j], acc[i][j]);
    __builtin_amdgcn_s_setprio(0);
    asm volatile("" ::: "memory");
    __builtin_amdgcn_s_barrier();
    // ---- P3: kh1, mi 4-7 (+ drain for next tile's buffer)
#pragma unroll
    for (int i = 0; i < 4; ++i) af[i] = *(const bf16x8*)(ldsA + (4 + i) * 1024 + swz1);
    asm volatile("" ::: "memory");
    asm volatile("s_waitcnt vmcnt(0)" ::: "memory");
    __builtin_amdgcn_s_barrier();
    asm volatile("s_waitcnt lgkmcnt(0)" ::: "memory");
    __builtin_amdgcn_sched_barrier(0);
    __builtin_amdgcn_s_setprio(1);
#pragma unroll
    for (int i = 0; i < 4; ++i)
#pragma unroll
      for (int j = 0; j < NJ; ++j) acc[4 + i][j] = mfma16(af[i], bf[j], acc[4 + i][j]);
    __builtin_amdgcn_s_setprio(0);
    asm volatile("" ::: "memory");
    __builtin_amdgcn_s_barrier();
  }
  // ---- epilogue
#pragma unroll
  for (int i = 0; i < 8; ++i)
#pragma unroll
    for (int j = 0; j < NJ; ++j) {
      int nn = n0 + wn * (BN / 4) + j * 16 + l15;
      int mmb = m0 + wm * 128 + i * 16 + g * 4;
      if (mode == 1) {
#pragma unroll
        for (int r = 0; r < 4; ++r)
          ((float*)Cv)[(size_t)(mmb + r) * N + nn] = acc[i][j][r];
      } else if (mode == 0) {
#pragma unroll
        for (int r = 0; r < 4; ++r)
          ((u16*)Cv)[(size_t)(mmb + r) * N + nn] = f2b(acc[i][j][r]);
      } else {
        u16x4 pk;
#pragma unroll
        for (int r = 0; r < 4; ++r) pk[r] = f2b(acc[i][j][r]);
        *(u16x4*)((u16*)Cv + (size_t)nn * 2048 + (size_t)(mmb >> 11) * 2097152 + (mmb & 2047)) = pk;
      }
    }
}

// Q/O projections: BN=192, grid (16,16) = 256 blocks = exactly one full round.
__global__ __launch_bounds__(512, 1) void gemm192_bf16(const u16* __restrict__ A, const u16* __restrict__ B,
                                                       u16* __restrict__ C, int N, int K) {
  int bx, by; swz_bid(bx, by);
  gemm256_body<192>(A, B, C, N, K, by * 256, bx * 192, 0);
}
__global__ __launch_bounds__(512, 1) void gemm192_f32(const u16* __restrict__ A, const u16* __restrict__ B,
                                                      float* __restrict__ C, int N, int K) {
  int bx, by; swz_bid(bx, by);
  gemm256_body<192>(A, B, C, N, K, by * 256, bx * 192, 1);
}
// K/V projections: BN=128, grid (16,16); bx<8 -> K (row-major), bx>=8 -> V (V^T out)
__global__ __launch_bounds__(512, 1) void gemm128_kv(const u16* __restrict__ A,
                                                     const u16* __restrict__ Bk, const u16* __restrict__ Bv,
                                                     u16* __restrict__ Ck, u16* __restrict__ Cv,
                                                     int K) {
  int bx, by; swz_bid(bx, by);
  bool isv = bx >= 8;
  gemm256_body<128>(A, isv ? Bv : Bk, isv ? Cv : Ck, 1024, K, by * 256, (bx & 7) * 128,
                    isv ? 2 : 0);
}

// ---------------- RoPE (in place, bf16) — K only ----------------
__global__ __launch_bounds__(256) void rope_kernel(u16* __restrict__ t, const float* __restrict__ fc,
                                                   const float* __restrict__ fs, int nheads, int total) {
  int idx = blockIdx.x * 256 + threadIdx.x;
  if (idx >= total) return;
  int c = idx & 7;
  int tmp = idx >> 3;
  int h = tmp % nheads;
  int row = tmp / nheads;
  int s = row & (S_LEN - 1);
  int d0 = c << 3;
  u16* base = t + (size_t)row * (nheads * 128) + h * 128;
  u16x8 lo = *(const u16x8*)(base + d0);
  u16x8 hi = *(const u16x8*)(base + 64 + d0);
  const float* cp = fc + s * 64 + d0;
  const float* sp = fs + s * 64 + d0;
  u16x8 olo, ohi;
#pragma unroll
  for (int j = 0; j < 8; ++j) {
    float cv = cp[j], sn = sp[j];
    float a = b2f(lo[j]), b = b2f(hi[j]);
    olo[j] = f2b(a * cv - b * sn);
    ohi[j] = f2b(b * cv + a * sn);
  }
  *(u16x8*)(base + d0) = olo;
  *(u16x8*)(base + 64 + d0) = ohi;
}

// ---------------- causal GQA flash attention (r8 verbatim — proven 176 us) ----------------
// grid: flat 384 blocks, XCD-GROUP-PINNED. Equal-work paired panels, K/V^T
// double-buffered via global_load_lds w/ pre-swizzled sources, register P via
// cvt_pk + shfl redistribution, defer-max, exp2 softmax, Q-RoPE fused.
__global__ __launch_bounds__(512) void attn_kernel(const u16* __restrict__ xq,
                                                   const u16* __restrict__ xk,
                                                   const u16* __restrict__ xvT,
                                                   const float* __restrict__ fc,
                                                   const float* __restrict__ fs,
                                                   u16* __restrict__ o) {
  __shared__ __align__(16) u16 smem[32768];     // 64 KB: K dbuf 32K + V^T dbuf 32K
  const int tid = threadIdx.x;
  const int w = tid >> 6, lane = tid & 63;
  const int l15 = lane & 15, g = lane >> 4;
  const int id = blockIdx.x;
  const int xcd = id & 7, slot = id >> 3;
  const int grp = xcd + 8 * (slot / 24);       // (b,kvh) group, 0..15
  const int jj = slot % 24;
  const int b = grp >> 3, kvh = grp & 7;
  const int h = kvh * 3 + jj % 3;
  const int bxx = jj / 3;                      // 0..7 (panel pair selector)
  const float sc2 = 0.08838834764831845f * 1.4426950408889634f;  // 1/sqrt(128)*log2e

  const u16* ksrc = xk + (size_t)b * 2097152 + kvh * 128;          // [s][1024]
  const u16* vsrc = xvT + (size_t)(b * 1024 + kvh * 128) * 2048;   // [d][2048]
  int koff[2], vofs[2], dst[2];
#pragma unroll
  for (int r = 0; r < 2; ++r) {
    int ck = r * 512 + tid;                    // K tile: 64 rows x 16 chunks
    int krow = ck >> 4, kj = (ck & 15) ^ (krow & 7);
    koff[r] = krow * 1024 + kj * 8;
    int cv = r * 512 + tid;                    // V^T tile: 128 rows x 8 chunks
    int vrow = cv >> 3, vj = (cv & 7) ^ (vrow & 7);
    vofs[r] = vrow * 2048 + vj * 8;
    dst[r] = (r * 512 + (tid & 448)) * 8;      // wave-uniform LDS chunk base
  }

  for (int panel = 0; panel < 2; ++panel) {
    const int qb = panel == 0 ? (15 - bxx) : bxx;
    const int q0 = qb * 128;
    const int qrow = q0 + w * 16 + l15;
    const u16* qptr = xq + (size_t)(b * S_LEN + qrow) * DM + h * 128;

    bf16x8 qf[4];
#pragma unroll
    for (int dcp = 0; dcp < 2; ++dcp) {
      u16x8 Lo = *(const u16x8*)(qptr + dcp * 32 + g * 8);
      u16x8 Hi = *(const u16x8*)(qptr + 64 + dcp * 32 + g * 8);
      const float* cp = fc + qrow * 64 + dcp * 32 + g * 8;
      const float* sp = fs + qrow * 64 + dcp * 32 + g * 8;
      bf16x8 qlo, qhi;
#pragma unroll
      for (int j = 0; j < 8; ++j) {
        float cv = cp[j], sn = sp[j];
        float a = b2f(Lo[j]), bb = b2f(Hi[j]);
        qlo[j] = (__bf16)((a * cv - bb * sn) * sc2);
        qhi[j] = (__bf16)((bb * cv + a * sn) * sc2);
      }
      qf[dcp] = qlo;
      qf[dcp + 2] = qhi;
    }

    u16 *sKc = smem, *sKn = smem + 8192;
    u16 *sVc = smem + 16384, *sVn = smem + 24576;

    f32x4 accO[8];
#pragma unroll
    for (int i = 0; i < 8; ++i) accO[i] = 0.f;
    float m = -1e30f, lsum = 0.f;
    const int nt = 2 * qb + 2;

#pragma unroll
    for (int r = 0; r < 2; ++r) gload16(ksrc + koff[r], sKc + dst[r]);
#pragma unroll
    for (int r = 0; r < 2; ++r) gload16(vsrc + vofs[r], sVc + dst[r]);
    __syncthreads();

    for (int t = 0; t < nt; ++t) {
      if (t + 1 < nt) {
        int k0n = (t + 1) * 64;
#pragma unroll
        for (int r = 0; r < 2; ++r) gload16(ksrc + (size_t)k0n * 1024 + koff[r], sKn + dst[r]);
#pragma unroll
        for (int r = 0; r < 2; ++r) gload16(vsrc + k0n + vofs[r], sVn + dst[r]);
      }
      if (64 * t <= q0 + w * 16 + 15) {         // wave-level causal skip
        f32x4 st[4];
        __builtin_amdgcn_s_setprio(1);
#pragma unroll
        for (int kt = 0; kt < 4; ++kt) {
          f32x4 a = 0.f;
          int row = kt * 16 + l15;
#pragma unroll
          for (int dc = 0; dc < 4; ++dc) {
            bf16x8 kf = *(const bf16x8*)(sKc + row * 128 + ((dc * 32 + g * 8) ^ ((row & 7) << 3)));
            a = mfma16(kf, qf[dc], a);
          }
          st[kt] = a;
        }
        __builtin_amdgcn_s_setprio(0);
        float sv[4][4];
        float pmax = -1e30f;
#pragma unroll
        for (int kt = 0; kt < 4; ++kt)
#pragma unroll
          for (int r = 0; r < 4; ++r) {
            float x = st[kt][r];
            if (t >= nt - 2) {
              int kk = t * 64 + kt * 16 + g * 4 + r;
              if (kk > qrow) x = -1e30f;
            }
            sv[kt][r] = x;
            pmax = fmaxf(pmax, x);
          }
        pmax = fmaxf(pmax, __shfl_xor(pmax, 16));
        pmax = fmaxf(pmax, __shfl_xor(pmax, 32));
        if (!__all(pmax - m <= 8.0f)) {        // defer-max
          float mnew = fmaxf(m, pmax);
          float corr = exp2f(m - mnew);
          lsum *= corr;
#pragma unroll
          for (int i = 0; i < 8; ++i) accO[i] *= corr;
          m = mnew;
        }
        float ps = 0.f;
        u32 pk2[4][2];
#pragma unroll
        for (int kt = 0; kt < 4; ++kt) {
          float e0 = exp2f(sv[kt][0] - m);
          float e1 = exp2f(sv[kt][1] - m);
          float e2 = exp2f(sv[kt][2] - m);
          float e3 = exp2f(sv[kt][3] - m);
          ps += (e0 + e1) + (e2 + e3);
          pk2[kt][0] = cvtpk(e0, e1);
          pk2[kt][1] = cvtpk(e2, e3);
        }
        ps += __shfl_xor(ps, 16);
        ps += __shfl_xor(ps, 32);
        lsum += ps;
        bf16x8 pf[2];
        const int srcA = ((g & 1) << 5) + l15;
        const bool h2 = (g >> 1) != 0;
#pragma unroll
        for (int ck = 0; ck < 2; ++ck) {
          u32 a0 = __shfl(pk2[2 * ck][0], srcA, 64);
          u32 a1 = __shfl(pk2[2 * ck][1], srcA, 64);
          u32 a2 = __shfl(pk2[2 * ck][0], srcA + 16, 64);
          u32 a3 = __shfl(pk2[2 * ck][1], srcA + 16, 64);
          u32 b0 = __shfl(pk2[2 * ck + 1][0], srcA, 64);
          u32 b1 = __shfl(pk2[2 * ck + 1][1], srcA, 64);
          u32 b2 = __shfl(pk2[2 * ck + 1][0], srcA + 16, 64);
          u32 b3 = __shfl(pk2[2 * ck + 1][1], srcA + 16, 64);
          u32x4 fr;
          fr[0] = h2 ? b0 : a0;
          fr[1] = h2 ? b1 : a1;
          fr[2] = h2 ? b2 : a2;
          fr[3] = h2 ? b3 : a3;
          pf[ck] = __builtin_bit_cast(bf16x8, fr);
        }
        __builtin_amdgcn_s_setprio(1);
#pragma unroll
        for (int dt = 0; dt < 8; ++dt) {
          int row = dt * 16 + l15;
#pragma unroll
          for (int ck = 0; ck < 2; ++ck) {
            bf16x8 vf = *(const bf16x8*)(sVc + row * 64 + ((ck * 32 + g * 8) ^ ((row & 7) << 3)));
            accO[dt] = mfma16(vf, pf[ck], accO[dt]);
          }
        }
        __builtin_amdgcn_s_setprio(0);
      }
      __syncthreads();
      u16* tk = sKc; sKc = sKn; sKn = tk;
      u16* tv = sVc; sVc = sVn; sVn = tv;
    }
    u16* sO = smem + w * 2048;
    float invl = 1.0f / lsum;
#pragma unroll
    for (int dt = 0; dt < 8; ++dt)
#pragma unroll
      for (int r = 0; r < 4; ++r) {
        int d = dt * 16 + g * 4 + r;
        sO[(l15 * 128 + d) ^ ((l15 & 7) << 3)] = f2b(accO[dt][r] * invl);
      }
#pragma unroll
    for (int p = 0; p < 4; ++p) {
      int idx = p * 64 + lane;
      int q = idx >> 4, d0 = (idx & 15) << 3;
      u32x4 v = *(const u32x4*)(sO + ((q * 128 + d0) ^ ((q & 7) << 3)));
      *(u32x4*)(o + (size_t)(b * S_LEN + q0 + w * 16 + q) * DM + h * 128 + d0) = v;
    }
    __syncthreads();
  }
}

// ---------------- launch ----------------
extern "C" void kernel_launch(void* const* d_in, const int* in_sizes, int n_in,
                              void* d_out, int out_size, void* d_ws, size_t ws_size,
                              hipStream_t stream) {
  const float* x  = (const float*)d_in[0];
  const float* fc = (const float*)d_in[1];
  const float* fs = (const float*)d_in[2];
  const float* wq = (const float*)d_in[4];
  const float* wk = (const float*)d_in[5];
  const float* wv = (const float*)d_in[6];
  const float* wo = (const float*)d_in[7];
  float* out = (float*)d_out;
  char* ws = (char*)d_ws;

  u16* xb  = (u16*)(ws);                 // x bf16      25,165,824
  u16* wqb = (u16*)(ws + 25165824);      // wq bf16     18,874,368
  u16* att = (u16*)(ws + 25165824);      // attn out (aliases wq/wk after death)
  u16* wkb = (u16*)(ws + 44040192);      // wk bf16      6,291,456
  u16* wvb = (u16*)(ws + 50331648);      // wv bf16      6,291,456
  u16* xqb = (u16*)(ws + 56623104);      // xq bf16     25,165,824
  u16* xkb = (u16*)(ws + 81788928);      // xk bf16      8,388,608
  u16* xvT = (u16*)(ws + 90177536);      // V^T bf16     8,388,608
  u16* wob = (u16*)(ws);                 // wo bf16 (aliases xb after death)

  cvt4_kernel<<<13824, 256, 0, stream>>>(x, xb, wq, wqb, wk, wkb, wv, wvb);

  gemm192_bf16<<<dim3(16, 16), 512, 0, stream>>>(xb, wqb, xqb, 3072, 3072);
  gemm128_kv<<<dim3(16, 16), 512, 0, stream>>>(xb, wkb, wvb, xkb, xvT, 3072);

  cvt_kernel<<<4608, 256, 0, stream>>>(wo, wob, 1179648);   // after gemm_kv (aliases xb)
  rope_kernel<<<1024, 256, 0, stream>>>(xkb, fc, fs, NKV, 4096 * NKV * 8);  // K only

  attn_kernel<<<dim3(384, 1, 1), 512, 0, stream>>>(xqb, xkb, xvT, fc, fs, att);

  gemm192_f32<<<dim3(16, 16), 512, 0, stream>>>(att, wob, out, 3072, 3072);
}

// Round 11
// 396.171 us; speedup vs baseline: 1.9281x; 1.0353x over previous
//
#include <hip/hip_runtime.h>

typedef unsigned short u16;
typedef unsigned int u32;
typedef __attribute__((ext_vector_type(8))) __bf16 bf16x8;
typedef __attribute__((ext_vector_type(4))) float f32x4;
typedef __attribute__((ext_vector_type(4))) u32 u32x4;
typedef __attribute__((ext_vector_type(8))) u16 u16x8;
typedef __attribute__((ext_vector_type(4))) u16 u16x4;

#define S_LEN 2048
#define DM 3072
#define NH 24
#define NKV 8

__device__ __forceinline__ u16 f2b(float f) {
  u32 u = __builtin_bit_cast(u32, f);
  u = u + 0x7FFFu + ((u >> 16) & 1u);
  return (u16)(u >> 16);
}
__device__ __forceinline__ float b2f(u16 h) {
  u32 u = ((u32)h) << 16;
  return __builtin_bit_cast(float, u);
}
__device__ __forceinline__ f32x4 mfma16(bf16x8 a, bf16x8 b, f32x4 c) {
  return __builtin_amdgcn_mfma_f32_16x16x32_bf16(a, b, c, 0, 0, 0);
}
__device__ __forceinline__ void gload16(const u16* g, u16* l) {
  __builtin_amdgcn_global_load_lds((const __attribute__((address_space(1))) void*)g,
                                   (__attribute__((address_space(3))) void*)l, 16, 0, 0);
}

// ---------------- f32 -> bf16 conversion ----------------
__device__ __forceinline__ void cvt_one(const float* __restrict__ s, u16* __restrict__ d, int j) {
  const f32x4* p = (const f32x4*)(s + (size_t)j * 8);
  f32x4 a = p[0], b = p[1];
  u16x8 o;
#pragma unroll
  for (int q = 0; q < 4; ++q) { o[q] = f2b(a[q]); o[q + 4] = f2b(b[q]); }
  *(u16x8*)(d + (size_t)j * 8) = o;
}
__global__ __launch_bounds__(256) void cvt_kernel(const float* __restrict__ s,
                                                  u16* __restrict__ d, int n8) {
  int i = blockIdx.x * 256 + threadIdx.x;
  if (i >= n8) return;
  cvt_one(s, d, i);
}
__global__ __launch_bounds__(256) void cvt4_kernel(const float* __restrict__ s0, u16* __restrict__ d0,
                                                   const float* __restrict__ s1, u16* __restrict__ d1,
                                                   const float* __restrict__ s2, u16* __restrict__ d2,
                                                   const float* __restrict__ s3, u16* __restrict__ d3) {
  int i = blockIdx.x * 256 + threadIdx.x;
  if (i < 1572864)      cvt_one(s0, d0, i);
  else if (i < 2752512) cvt_one(s1, d1, i - 1572864);
  else if (i < 3145728) cvt_one(s2, d2, i - 2752512);
  else                  cvt_one(s3, d3, i - 3145728);
}

// ---------------- XCD-aware block swizzle ----------------
__device__ __forceinline__ void swz_bid(int& bx, int& by) {
  int gx = gridDim.x;
  int tot = gx * gridDim.y;          // must be divisible by 8
  int id = blockIdx.y * gx + blockIdx.x;
  int cpx = tot >> 3;
  int s = (id & 7) * cpx + (id >> 3);
  bx = s % gx;
  by = s / gx;
}

// ---------------- phase-interleaved GEMM, BM=256, BN in {192,128} (r10-proven) ----------------
template <int BN>
__device__ __forceinline__ void gemm256_body(const u16* __restrict__ A, const u16* __restrict__ B,
                                             void* __restrict__ Cv, int N, int K,
                                             int m0, int n0, int mode) {
  constexpr int NJ = BN / 64;
  constexpr int NSB = BN / 64;
  constexpr int BBUF = NSB * 4096;
  __shared__ __align__(16) u16 lds[32768 + 2 * BBUF];
  const int tid = threadIdx.x;
  const int lane = tid & 63;
  const int w = tid >> 6;
  const int l15 = lane & 15, g = lane >> 4;
  const int wm = w >> 2, wn = w & 3;
  const int srow = tid >> 3;
  const int scol = ((tid & 7) ^ (srow & 7)) * 8;
  const u16* aS = A + (size_t)(m0 + srow) * K + scol;
  const u16* bS = B + (size_t)(n0 + srow) * K + scol;
  const int sdst = (tid & 448) * 8;
  const int swz0 = (g ^ (l15 & 7)) * 8;
  const int swz1 = ((4 + g) ^ (l15 & 7)) * 8;
  const int aB0 = wm * 8192 + l15 * 64;
  const int bB0 = wn * (BN / 4) * 64 + l15 * 64;

  f32x4 acc[8][NJ];
#pragma unroll
  for (int i = 0; i < 8; ++i)
#pragma unroll
    for (int j = 0; j < NJ; ++j) acc[i][j] = 0.f;

  auto stage = [&](int k0, int bsel) {
#pragma unroll
    for (int s = 0; s < 4; ++s)
      gload16(aS + (size_t)(s * 64) * K + k0, lds + bsel * 16384 + s * 4096 + sdst);
#pragma unroll
    for (int s = 0; s < NSB; ++s)
      gload16(bS + (size_t)(s * 64) * K + k0, lds + 32768 + bsel * BBUF + s * 4096 + sdst);
  };

  stage(0, 0);
  asm volatile("s_waitcnt vmcnt(0)" ::: "memory");
  __builtin_amdgcn_s_barrier();

  for (int t = 0; t < 48; ++t) {
    const int bsel = t & 1;
    const u16* ldsA = lds + bsel * 16384 + aB0;
    const u16* ldsB = lds + 32768 + bsel * BBUF + bB0;
    bf16x8 af[4], bf[NJ];
    // ---- P0: kh0, mi 0-3 (+ stage next tile)
#pragma unroll
    for (int i = 0; i < 4; ++i) af[i] = *(const bf16x8*)(ldsA + i * 1024 + swz0);
#pragma unroll
    for (int j = 0; j < NJ; ++j) bf[j] = *(const bf16x8*)(ldsB + j * 1024 + swz0);
    if (t < 47) stage((t + 1) * 64, bsel ^ 1);
    asm volatile("" ::: "memory");
    __builtin_amdgcn_s_barrier();
    asm volatile("s_waitcnt lgkmcnt(0)" ::: "memory");
    __builtin_amdgcn_sched_barrier(0);
    __builtin_amdgcn_s_setprio(1);
#pragma unroll
    for (int i = 0; i < 4; ++i)
#pragma unroll
      for (int j = 0; j < NJ; ++j) acc[i][j] = mfma16(af[i], bf[j], acc[i][j]);
    __builtin_amdgcn_s_setprio(0);
    asm volatile("" ::: "memory");
    __builtin_amdgcn_s_barrier();
    // ---- P1: kh0, mi 4-7
#pragma unroll
    for (int i = 0; i < 4; ++i) af[i] = *(const bf16x8*)(ldsA + (4 + i) * 1024 + swz0);
    asm volatile("" ::: "memory");
    __builtin_amdgcn_s_barrier();
    asm volatile("s_waitcnt lgkmcnt(0)" ::: "memory");
    __builtin_amdgcn_sched_barrier(0);
    __builtin_amdgcn_s_setprio(1);
#pragma unroll
    for (int i = 0; i < 4; ++i)
#pragma unroll
      for (int j = 0; j < NJ; ++j) acc[4 + i][j] = mfma16(af[i], bf[j], acc[4 + i][j]);
    __builtin_amdgcn_s_setprio(0);
    asm volatile("" ::: "memory");
    __builtin_amdgcn_s_barrier();
    // ---- P2: kh1, mi 0-3
#pragma unroll
    for (int i = 0; i < 4; ++i) af[i] = *(const bf16x8*)(ldsA + i * 1024 + swz1);
#pragma unroll
    for (int j = 0; j < NJ; ++j) bf[j] = *(const bf16x8*)(ldsB + j * 1024 + swz1);
    asm volatile("" ::: "memory");
    __builtin_amdgcn_s_barrier();
    asm volatile("s_waitcnt lgkmcnt(0)" ::: "memory");
    __builtin_amdgcn_sched_barrier(0);
    __builtin_amdgcn_s_setprio(1);
#pragma unroll
    for (int i = 0; i < 4; ++i)
#pragma unroll
      for (int j = 0; j < NJ; ++j) acc[i][j] = mfma16(af[i], bf[j], acc[i][j]);
    __builtin_amdgcn_s_setprio(0);
    asm volatile("" ::: "memory");
    __builtin_amdgcn_s_barrier();
    // ---- P3: kh1, mi 4-7 (+ drain for next tile's buffer)
#pragma unroll
    for (int i = 0; i < 4; ++i) af[i] = *(const bf16x8*)(ldsA + (4 + i) * 1024 + swz1);
    asm volatile("" ::: "memory");
    asm volatile("s_waitcnt vmcnt(0)" ::: "memory");
    __builtin_amdgcn_s_barrier();
    asm volatile("s_waitcnt lgkmcnt(0)" ::: "memory");
    __builtin_amdgcn_sched_barrier(0);
    __builtin_amdgcn_s_setprio(1);
#pragma unroll
    for (int i = 0; i < 4; ++i)
#pragma unroll
      for (int j = 0; j < NJ; ++j) acc[4 + i][j] = mfma16(af[i], bf[j], acc[4 + i][j]);
    __builtin_amdgcn_s_setprio(0);
    asm volatile("" ::: "memory");
    __builtin_amdgcn_s_barrier();
  }
  // ---- epilogue
#pragma unroll
  for (int i = 0; i < 8; ++i)
#pragma unroll
    for (int j = 0; j < NJ; ++j) {
      int nn = n0 + wn * (BN / 4) + j * 16 + l15;
      int mmb = m0 + wm * 128 + i * 16 + g * 4;
      if (mode == 1) {
#pragma unroll
        for (int r = 0; r < 4; ++r)
          ((float*)Cv)[(size_t)(mmb + r) * N + nn] = acc[i][j][r];
      } else if (mode == 0) {
#pragma unroll
        for (int r = 0; r < 4; ++r)
          ((u16*)Cv)[(size_t)(mmb + r) * N + nn] = f2b(acc[i][j][r]);
      } else {
        u16x4 pk;
#pragma unroll
        for (int r = 0; r < 4; ++r) pk[r] = f2b(acc[i][j][r]);
        *(u16x4*)((u16*)Cv + (size_t)nn * 2048 + (size_t)(mmb >> 11) * 2097152 + (mmb & 2047)) = pk;
      }
    }
}

__global__ __launch_bounds__(512, 1) void gemm192_bf16(const u16* __restrict__ A, const u16* __restrict__ B,
                                                       u16* __restrict__ C, int N, int K) {
  int bx, by; swz_bid(bx, by);
  gemm256_body<192>(A, B, C, N, K, by * 256, bx * 192, 0);
}
__global__ __launch_bounds__(512, 1) void gemm192_f32(const u16* __restrict__ A, const u16* __restrict__ B,
                                                      float* __restrict__ C, int N, int K) {
  int bx, by; swz_bid(bx, by);
  gemm256_body<192>(A, B, C, N, K, by * 256, bx * 192, 1);
}
__global__ __launch_bounds__(512, 1) void gemm128_kv(const u16* __restrict__ A,
                                                     const u16* __restrict__ Bk, const u16* __restrict__ Bv,
                                                     u16* __restrict__ Ck, u16* __restrict__ Cv,
                                                     int K) {
  int bx, by; swz_bid(bx, by);
  bool isv = bx >= 8;
  gemm256_body<128>(A, isv ? Bv : Bk, isv ? Cv : Ck, 1024, K, by * 256, (bx & 7) * 128,
                    isv ? 2 : 0);
}

// ---------------- RoPE (in place, bf16) — K only ----------------
__global__ __launch_bounds__(256) void rope_kernel(u16* __restrict__ t, const float* __restrict__ fc,
                                                   const float* __restrict__ fs, int nheads, int total) {
  int idx = blockIdx.x * 256 + threadIdx.x;
  if (idx >= total) return;
  int c = idx & 7;
  int tmp = idx >> 3;
  int h = tmp % nheads;
  int row = tmp / nheads;
  int s = row & (S_LEN - 1);
  int d0 = c << 3;
  u16* base = t + (size_t)row * (nheads * 128) + h * 128;
  u16x8 lo = *(const u16x8*)(base + d0);
  u16x8 hi = *(const u16x8*)(base + 64 + d0);
  const float* cp = fc + s * 64 + d0;
  const float* sp = fs + s * 64 + d0;
  u16x8 olo, ohi;
#pragma unroll
  for (int j = 0; j < 8; ++j) {
    float cv = cp[j], sn = sp[j];
    float a = b2f(lo[j]), b = b2f(hi[j]);
    olo[j] = f2b(a * cv - b * sn);
    ohi[j] = f2b(b * cv + a * sn);
  }
  *(u16x8*)(base + d0) = olo;
  *(u16x8*)(base + 64 + d0) = ohi;
}

// ---------------- causal GQA flash attention — 2 q-sets/wave, 4-wave blocks ----------------
// Each wave serves 32 q-rows (two 16-row sets) so every K/V b128 LDS read feeds
// TWO MFMAs (halves LDS reads per q — the measured wall). P via wave-local
// XOR-swizzled LDS (r3-proven: 4 b64 writes + 2 b128 reads per set) instead of
// 16 conflicted bpermutes. 80 KB LDS -> 2 blocks/CU. XCD-group-pinned grid 384,
// equal-work paired panels, dbuf K/V^T global_load_lds staging, defer-max,
// exp2 softmax, fused Q-RoPE — all carried from r8.
__global__ __launch_bounds__(256, 2) void attn_kernel(const u16* __restrict__ xq,
                                                      const u16* __restrict__ xk,
                                                      const u16* __restrict__ xvT,
                                                      const float* __restrict__ fc,
                                                      const float* __restrict__ fs,
                                                      u16* __restrict__ o) {
  __shared__ __align__(16) u16 smem[40960];    // 80 KB: K dbuf 32K + V dbuf 32K + P 16K
  const int tid = threadIdx.x;
  const int w = tid >> 6, lane = tid & 63;
  const int l15 = lane & 15, g = lane >> 4;
  const int id = blockIdx.x;
  const int xcd = id & 7, slot = id >> 3;
  const int grp = xcd + 8 * (slot / 24);       // (b,kvh) group, 0..15
  const int jj = slot % 24;
  const int b = grp >> 3, kvh = grp & 7;
  const int h = kvh * 3 + jj % 3;
  const int bxx = jj / 3;                      // 0..7 (panel pair selector)
  const float sc2 = 0.08838834764831845f * 1.4426950408889634f;  // 1/sqrt(128)*log2e

  const u16* ksrc = xk + (size_t)b * 2097152 + kvh * 128;          // [s][1024]
  const u16* vsrc = xvT + (size_t)(b * 1024 + kvh * 128) * 2048;   // [d][2048]
  int koff[4], vofs[4], dst4[4];
#pragma unroll
  for (int r = 0; r < 4; ++r) {
    int c = r * 256 + tid;
    int krow = c >> 4, kj = (c & 15) ^ (krow & 7);   // K: 64 rows x 16 chunks
    koff[r] = krow * 1024 + kj * 8;
    int vrow = c >> 3, vj = (c & 7) ^ (vrow & 7);    // V^T: 128 rows x 8 chunks
    vofs[r] = vrow * 2048 + vj * 8;
    dst4[r] = (r * 256 + (tid & 192)) * 8;           // wave-uniform LDS chunk base
  }
  u16* sPw = smem + 32768 + w * 2048;          // per-wave P: 2 sets x 1024 u16
  const int pxr = (l15 & 7) << 3;

  for (int panel = 0; panel < 2; ++panel) {
    const int qb = panel == 0 ? (15 - bxx) : bxx;
    const int q0 = qb * 128;

    // Q load + fused RoPE + pre-scale, 2 sets
    bf16x8 qf[2][4];
#pragma unroll
    for (int s = 0; s < 2; ++s) {
      const int qrow = q0 + w * 32 + s * 16 + l15;
      const u16* qptr = xq + (size_t)(b * S_LEN + qrow) * DM + h * 128;
#pragma unroll
      for (int dcp = 0; dcp < 2; ++dcp) {
        u16x8 Lo = *(const u16x8*)(qptr + dcp * 32 + g * 8);
        u16x8 Hi = *(const u16x8*)(qptr + 64 + dcp * 32 + g * 8);
        const float* cp = fc + qrow * 64 + dcp * 32 + g * 8;
        const float* sp = fs + qrow * 64 + dcp * 32 + g * 8;
        bf16x8 qlo, qhi;
#pragma unroll
        for (int j = 0; j < 8; ++j) {
          float cv = cp[j], sn = sp[j];
          float a = b2f(Lo[j]), bb = b2f(Hi[j]);
          qlo[j] = (__bf16)((a * cv - bb * sn) * sc2);
          qhi[j] = (__bf16)((bb * cv + a * sn) * sc2);
        }
        qf[s][dcp] = qlo;
        qf[s][dcp + 2] = qhi;
      }
    }

    u16 *sKc = smem, *sKn = smem + 8192;
    u16 *sVc = smem + 16384, *sVn = smem + 24576;

    f32x4 accO[2][8];
#pragma unroll
    for (int s = 0; s < 2; ++s)
#pragma unroll
      for (int i = 0; i < 8; ++i) accO[s][i] = 0.f;
    float m_[2] = {-1e30f, -1e30f}, ls_[2] = {0.f, 0.f};
    const int nt = 2 * qb + 2;

#pragma unroll
    for (int r = 0; r < 4; ++r) gload16(ksrc + koff[r], sKc + dst4[r]);
#pragma unroll
    for (int r = 0; r < 4; ++r) gload16(vsrc + vofs[r], sVc + dst4[r]);
    __syncthreads();

    for (int t = 0; t < nt; ++t) {
      if (t + 1 < nt) {
        int k0n = (t + 1) * 64;
#pragma unroll
        for (int r = 0; r < 4; ++r) gload16(ksrc + (size_t)k0n * 1024 + koff[r], sKn + dst4[r]);
#pragma unroll
        for (int r = 0; r < 4; ++r) gload16(vsrc + k0n + vofs[r], sVn + dst4[r]);
      }
      if (64 * t <= q0 + w * 32 + 31) {         // wave-level causal skip
        // QK^T both sets: each kf read feeds 2 MFMAs
        f32x4 st[2][4];
        __builtin_amdgcn_s_setprio(1);
#pragma unroll
        for (int kt = 0; kt < 4; ++kt) {
          int row = kt * 16 + l15;
          bf16x8 kf[4];
#pragma unroll
          for (int dc = 0; dc < 4; ++dc)
            kf[dc] = *(const bf16x8*)(sKc + row * 128 + ((dc * 32 + g * 8) ^ ((row & 7) << 3)));
          f32x4 a0 = 0.f, a1 = 0.f;
#pragma unroll
          for (int dc = 0; dc < 4; ++dc) {
            a0 = mfma16(kf[dc], qf[0][dc], a0);
            a1 = mfma16(kf[dc], qf[1][dc], a1);
          }
          st[0][kt] = a0;
          st[1][kt] = a1;
        }
        __builtin_amdgcn_s_setprio(0);
        // softmax per set (mask in place, defer-max, exp2, P to wave-local LDS)
#pragma unroll
        for (int s = 0; s < 2; ++s) {
          const int qrow = q0 + w * 32 + s * 16 + l15;
          float pmax = -1e30f;
#pragma unroll
          for (int kt = 0; kt < 4; ++kt)
#pragma unroll
            for (int r = 0; r < 4; ++r) {
              float x = st[s][kt][r];
              if (t >= nt - 2) {
                int kk = t * 64 + kt * 16 + g * 4 + r;
                if (kk > qrow) x = -1e30f;
              }
              st[s][kt][r] = x;
              pmax = fmaxf(pmax, x);
            }
          pmax = fmaxf(pmax, __shfl_xor(pmax, 16));
          pmax = fmaxf(pmax, __shfl_xor(pmax, 32));
          if (!__all(pmax - m_[s] <= 8.0f)) {  // defer-max
            float mnew = fmaxf(m_[s], pmax);
            float corr = exp2f(m_[s] - mnew);
            ls_[s] *= corr;
#pragma unroll
            for (int i = 0; i < 8; ++i) accO[s][i] *= corr;
            m_[s] = mnew;
          }
          float ps = 0.f;
#pragma unroll
          for (int kt = 0; kt < 4; ++kt) {
            u16x4 pk;
#pragma unroll
            for (int r = 0; r < 4; ++r) {
              float p = exp2f(st[s][kt][r] - m_[s]);
              ps += p;
              pk[r] = f2b(p);
            }
            *(u16x4*)(sPw + s * 1024 + ((l15 * 64 + kt * 16 + g * 4) ^ pxr)) = pk;
          }
          ps += __shfl_xor(ps, 16);
          ps += __shfl_xor(ps, 32);
          ls_[s] += ps;
        }
        // P fragments (wave-local LDS, lgkm-ordered by compiler)
        bf16x8 pf[2][2];
#pragma unroll
        for (int s = 0; s < 2; ++s)
#pragma unroll
          for (int ck = 0; ck < 2; ++ck)
            pf[s][ck] = *(const bf16x8*)(sPw + s * 1024 + ((l15 * 64 + ck * 32 + g * 8) ^ pxr));
        // PV both sets: each vf read feeds 2 MFMAs
        __builtin_amdgcn_s_setprio(1);
#pragma unroll
        for (int dt = 0; dt < 8; ++dt) {
          int row = dt * 16 + l15;
#pragma unroll
          for (int ck = 0; ck < 2; ++ck) {
            bf16x8 vf = *(const bf16x8*)(sVc + row * 64 + ((ck * 32 + g * 8) ^ ((row & 7) << 3)));
            accO[0][dt] = mfma16(vf, pf[0][ck], accO[0][dt]);
            accO[1][dt] = mfma16(vf, pf[1][ck], accO[1][dt]);
          }
        }
        __builtin_amdgcn_s_setprio(0);
      }
      __syncthreads();                          // drains stage vmcnt + cur reads done
      u16* tk = sKc; sKc = sKn; sKn = tk;
      u16* tv = sVc; sVc = sVn; sVn = tv;
    }
    // epilogue: per-wave [32 q][128 d] transpose in (dead) K/V LDS region
    u16* sOw = smem + w * 8192;
#pragma unroll
    for (int s = 0; s < 2; ++s) {
      float invl = 1.0f / ls_[s];
#pragma unroll
      for (int dt = 0; dt < 8; ++dt)
#pragma unroll
        for (int r = 0; r < 4; ++r) {
          int d = dt * 16 + g * 4 + r;
          sOw[((s * 16 + l15) * 128 + d) ^ pxr] = f2b(accO[s][dt][r] * invl);
        }
    }
#pragma unroll
    for (int p = 0; p < 8; ++p) {
      int idx = p * 64 + lane;
      int q = idx >> 4, c = idx & 15;
      int j = c ^ (q & 7);
      u32x4 v = *(const u32x4*)(sOw + q * 128 + j * 8);
      *(u32x4*)(o + (size_t)(b * S_LEN + q0 + w * 32 + q) * DM + h * 128 + c * 8) = v;
    }
    __syncthreads();                            // all epilogue LDS reads done before next panel restages
  }
}

// ---------------- launch ----------------
extern "C" void kernel_launch(void* const* d_in, const int* in_sizes, int n_in,
                              void* d_out, int out_size, void* d_ws, size_t ws_size,
                              hipStream_t stream) {
  const float* x  = (const float*)d_in[0];
  const float* fc = (const float*)d_in[1];
  const float* fs = (const float*)d_in[2];
  const float* wq = (const float*)d_in[4];
  const float* wk = (const float*)d_in[5];
  const float* wv = (const float*)d_in[6];
  const float* wo = (const float*)d_in[7];
  float* out = (float*)d_out;
  char* ws = (char*)d_ws;

  u16* xb  = (u16*)(ws);                 // x bf16      25,165,824
  u16* wqb = (u16*)(ws + 25165824);      // wq bf16     18,874,368
  u16* att = (u16*)(ws + 25165824);      // attn out (aliases wq/wk after death)
  u16* wkb = (u16*)(ws + 44040192);      // wk bf16      6,291,456
  u16* wvb = (u16*)(ws + 50331648);      // wv bf16      6,291,456
  u16* xqb = (u16*)(ws + 56623104);      // xq bf16     25,165,824
  u16* xkb = (u16*)(ws + 81788928);      // xk bf16      8,388,608
  u16* xvT = (u16*)(ws + 90177536);      // V^T bf16     8,388,608
  u16* wob = (u16*)(ws);                 // wo bf16 (aliases xb after death)

  cvt4_kernel<<<13824, 256, 0, stream>>>(x, xb, wq, wqb, wk, wkb, wv, wvb);

  gemm192_bf16<<<dim3(16, 16), 512, 0, stream>>>(xb, wqb, xqb, 3072, 3072);
  gemm128_kv<<<dim3(16, 16), 512, 0, stream>>>(xb, wkb, wvb, xkb, xvT, 3072);

  cvt_kernel<<<4608, 256, 0, stream>>>(wo, wob, 1179648);   // after gemm_kv (aliases xb)
  rope_kernel<<<1024, 256, 0, stream>>>(xkb, fc, fs, NKV, 4096 * NKV * 8);  // K only

  attn_kernel<<<dim3(384, 1, 1), 256, 0, stream>>>(xqb, xkb, xvT, fc, fs, att);

  gemm192_f32<<<dim3(16, 16), 512, 0, stream>>>(att, wob, out, 3072, 3072);
}

// Round 12
// 341.395 us; speedup vs baseline: 2.2375x; 1.1604x over previous
//
#include <hip/hip_runtime.h>

typedef unsigned short u16;
typedef unsigned int u32;
typedef __attribute__((ext_vector_type(8))) __bf16 bf16x8;
typedef __attribute__((ext_vector_type(4))) float f32x4;
typedef __attribute__((ext_vector_type(4))) u32 u32x4;
typedef __attribute__((ext_vector_type(8))) u16 u16x8;
typedef __attribute__((ext_vector_type(4))) u16 u16x4;

#define S_LEN 2048
#define DM 3072
#define NH 24
#define NKV 8

__device__ __forceinline__ u16 f2b(float f) {
  u32 u = __builtin_bit_cast(u32, f);
  u = u + 0x7FFFu + ((u >> 16) & 1u);
  return (u16)(u >> 16);
}
__device__ __forceinline__ float b2f(u16 h) {
  u32 u = ((u32)h) << 16;
  return __builtin_bit_cast(float, u);
}
__device__ __forceinline__ f32x4 mfma16(bf16x8 a, bf16x8 b, f32x4 c) {
  return __builtin_amdgcn_mfma_f32_16x16x32_bf16(a, b, c, 0, 0, 0);
}
__device__ __forceinline__ void gload16(const u16* g, u16* l) {
  __builtin_amdgcn_global_load_lds((const __attribute__((address_space(1))) void*)g,
                                   (__attribute__((address_space(3))) void*)l, 16, 0, 0);
}

// ---------------- f32 -> bf16 conversion ----------------
__device__ __forceinline__ void cvt_one(const float* __restrict__ s, u16* __restrict__ d, int j) {
  const f32x4* p = (const f32x4*)(s + (size_t)j * 8);
  f32x4 a = p[0], b = p[1];
  u16x8 o;
#pragma unroll
  for (int q = 0; q < 4; ++q) { o[q] = f2b(a[q]); o[q + 4] = f2b(b[q]); }
  *(u16x8*)(d + (size_t)j * 8) = o;
}
__global__ __launch_bounds__(256) void cvt4_kernel(const float* __restrict__ s0, u16* __restrict__ d0,
                                                   const float* __restrict__ s1, u16* __restrict__ d1,
                                                   const float* __restrict__ s2, u16* __restrict__ d2,
                                                   const float* __restrict__ s3, u16* __restrict__ d3) {
  int i = blockIdx.x * 256 + threadIdx.x;
  if (i < 1572864)      cvt_one(s0, d0, i);
  else if (i < 2752512) cvt_one(s1, d1, i - 1572864);
  else if (i < 3145728) cvt_one(s2, d2, i - 2752512);
  else                  cvt_one(s3, d3, i - 3145728);
}

// ---------------- XCD-aware block swizzle ----------------
__device__ __forceinline__ void swz_bid(int& bx, int& by) {
  int gx = gridDim.x;
  int tot = gx * gridDim.y;          // must be divisible by 8
  int id = blockIdx.y * gx + blockIdx.x;
  int cpx = tot >> 3;
  int s = (id & 7) * cpx + (id >> 3);
  bx = s % gx;
  by = s / gx;
}

// ---------------- phase-interleaved GEMM body (LDS passed in) ----------------
// C[m,n] = sum_k A[m,k]*B[n,k], row-major over K (K=3072, 48 K-tiles of 64).
// BM=256, BN in {192,128}; 512 threads = 8 waves (2M x 4N). LDS rows linear,
// chunk^(row&7) swizzle, pre-swizzled sources. 4 phases/K-tile.
// modes: 0 bf16, 1 f32, 2 V^T bf16. LDS requirement: 32768 + 2*BN*64 u16.
template <int BN>
__device__ __forceinline__ void gemm256_body(u16* __restrict__ lds,
                                             const u16* __restrict__ A, const u16* __restrict__ B,
                                             void* __restrict__ Cv, int N, int K,
                                             int m0, int n0, int mode) {
  constexpr int NJ = BN / 64;
  constexpr int NSB = BN / 64;
  constexpr int BBUF = NSB * 4096;
  const int tid = threadIdx.x;
  const int lane = tid & 63;
  const int w = tid >> 6;
  const int l15 = lane & 15, g = lane >> 4;
  const int wm = w >> 2, wn = w & 3;
  const int srow = tid >> 3;
  const int scol = ((tid & 7) ^ (srow & 7)) * 8;
  const u16* aS = A + (size_t)(m0 + srow) * K + scol;
  const u16* bS = B + (size_t)(n0 + srow) * K + scol;
  const int sdst = (tid & 448) * 8;
  const int swz0 = (g ^ (l15 & 7)) * 8;
  const int swz1 = ((4 + g) ^ (l15 & 7)) * 8;
  const int aB0 = wm * 8192 + l15 * 64;
  const int bB0 = wn * (BN / 4) * 64 + l15 * 64;

  f32x4 acc[8][NJ];
#pragma unroll
  for (int i = 0; i < 8; ++i)
#pragma unroll
    for (int j = 0; j < NJ; ++j) acc[i][j] = 0.f;

  auto stage = [&](int k0, int bsel) {
#pragma unroll
    for (int s = 0; s < 4; ++s)
      gload16(aS + (size_t)(s * 64) * K + k0, lds + bsel * 16384 + s * 4096 + sdst);
#pragma unroll
    for (int s = 0; s < NSB; ++s)
      gload16(bS + (size_t)(s * 64) * K + k0, lds + 32768 + bsel * BBUF + s * 4096 + sdst);
  };

  stage(0, 0);
  asm volatile("s_waitcnt vmcnt(0)" ::: "memory");
  __builtin_amdgcn_s_barrier();

  for (int t = 0; t < 48; ++t) {
    const int bsel = t & 1;
    const u16* ldsA = lds + bsel * 16384 + aB0;
    const u16* ldsB = lds + 32768 + bsel * BBUF + bB0;
    bf16x8 af[4], bf[NJ];
    // ---- P0: kh0, mi 0-3 (+ stage next tile)
#pragma unroll
    for (int i = 0; i < 4; ++i) af[i] = *(const bf16x8*)(ldsA + i * 1024 + swz0);
#pragma unroll
    for (int j = 0; j < NJ; ++j) bf[j] = *(const bf16x8*)(ldsB + j * 1024 + swz0);
    if (t < 47) stage((t + 1) * 64, bsel ^ 1);
    asm volatile("" ::: "memory");
    __builtin_amdgcn_s_barrier();
    asm volatile("s_waitcnt lgkmcnt(0)" ::: "memory");
    __builtin_amdgcn_sched_barrier(0);
    __builtin_amdgcn_s_setprio(1);
#pragma unroll
    for (int i = 0; i < 4; ++i)
#pragma unroll
      for (int j = 0; j < NJ; ++j) acc[i][j] = mfma16(af[i], bf[j], acc[i][j]);
    __builtin_amdgcn_s_setprio(0);
    asm volatile("" ::: "memory");
    __builtin_amdgcn_s_barrier();
    // ---- P1: kh0, mi 4-7
#pragma unroll
    for (int i = 0; i < 4; ++i) af[i] = *(const bf16x8*)(ldsA + (4 + i) * 1024 + swz0);
    asm volatile("" ::: "memory");
    __builtin_amdgcn_s_barrier();
    asm volatile("s_waitcnt lgkmcnt(0)" ::: "memory");
    __builtin_amdgcn_sched_barrier(0);
    __builtin_amdgcn_s_setprio(1);
#pragma unroll
    for (int i = 0; i < 4; ++i)
#pragma unroll
      for (int j = 0; j < NJ; ++j) acc[4 + i][j] = mfma16(af[i], bf[j], acc[4 + i][j]);
    __builtin_amdgcn_s_setprio(0);
    asm volatile("" ::: "memory");
    __builtin_amdgcn_s_barrier();
    // ---- P2: kh1, mi 0-3
#pragma unroll
    for (int i = 0; i < 4; ++i) af[i] = *(const bf16x8*)(ldsA + i * 1024 + swz1);
#pragma unroll
    for (int j = 0; j < NJ; ++j) bf[j] = *(const bf16x8*)(ldsB + j * 1024 + swz1);
    asm volatile("" ::: "memory");
    __builtin_amdgcn_s_barrier();
    asm volatile("s_waitcnt lgkmcnt(0)" ::: "memory");
    __builtin_amdgcn_sched_barrier(0);
    __builtin_amdgcn_s_setprio(1);
#pragma unroll
    for (int i = 0; i < 4; ++i)
#pragma unroll
      for (int j = 0; j < NJ; ++j) acc[i][j] = mfma16(af[i], bf[j], acc[i][j]);
    __builtin_amdgcn_s_setprio(0);
    asm volatile("" ::: "memory");
    __builtin_amdgcn_s_barrier();
    // ---- P3: kh1, mi 4-7 (+ drain for next tile's buffer)
#pragma unroll
    for (int i = 0; i < 4; ++i) af[i] = *(const bf16x8*)(ldsA + (4 + i) * 1024 + swz1);
    asm volatile("" ::: "memory");
    asm volatile("s_waitcnt vmcnt(0)" ::: "memory");
    __builtin_amdgcn_s_barrier();
    asm volatile("s_waitcnt lgkmcnt(0)" ::: "memory");
    __builtin_amdgcn_sched_barrier(0);
    __builtin_amdgcn_s_setprio(1);
#pragma unroll
    for (int i = 0; i < 4; ++i)
#pragma unroll
      for (int j = 0; j < NJ; ++j) acc[4 + i][j] = mfma16(af[i], bf[j], acc[4 + i][j]);
    __builtin_amdgcn_s_setprio(0);
    asm volatile("" ::: "memory");
    __builtin_amdgcn_s_barrier();
  }
  // ---- epilogue
#pragma unroll
  for (int i = 0; i < 8; ++i)
#pragma unroll
    for (int j = 0; j < NJ; ++j) {
      int nn = n0 + wn * (BN / 4) + j * 16 + l15;
      int mmb = m0 + wm * 128 + i * 16 + g * 4;
      if (mode == 1) {
#pragma unroll
        for (int r = 0; r < 4; ++r)
          ((float*)Cv)[(size_t)(mmb + r) * N + nn] = acc[i][j][r];
      } else if (mode == 0) {
#pragma unroll
        for (int r = 0; r < 4; ++r)
          ((u16*)Cv)[(size_t)(mmb + r) * N + nn] = f2b(acc[i][j][r]);
      } else {
        u16x4 pk;
#pragma unroll
        for (int r = 0; r < 4; ++r) pk[r] = f2b(acc[i][j][r]);
        *(u16x4*)((u16*)Cv + (size_t)nn * 2048 + (size_t)(mmb >> 11) * 2097152 + (mmb & 2047)) = pk;
      }
    }
}

// merged Q-proj + KV-proj: grid 512. ids 0-255 -> Q (BN=192), 256-511 -> K/V (BN=128).
__global__ __launch_bounds__(512, 1) void gemm_qkv(const u16* __restrict__ A,
                                                   const u16* __restrict__ Bq, u16* __restrict__ Cq,
                                                   const u16* __restrict__ Bk, const u16* __restrict__ Bv,
                                                   u16* __restrict__ Ck, u16* __restrict__ Cv, int K) {
  __shared__ __align__(16) u16 lds[57344];     // 112 KB (union of both variants)
  int id = blockIdx.x;
  if (id < 256) {
    int s = (id & 7) * 32 + (id >> 3);
    gemm256_body<192>(lds, A, Bq, Cq, 3072, K, (s / 16) * 256, (s % 16) * 192, 0);
  } else {
    id -= 256;
    int s = (id & 7) * 32 + (id >> 3);
    int bx = s % 16, by = s / 16;
    bool isv = bx >= 8;
    gemm256_body<128>(lds, A, isv ? Bv : Bk, isv ? Cv : Ck, 1024, K, by * 256, (bx & 7) * 128,
                      isv ? 2 : 0);
  }
}
// O-projection (f32 out), grid (16,16)
__global__ __launch_bounds__(512, 1) void gemm192_f32(const u16* __restrict__ A, const u16* __restrict__ B,
                                                      float* __restrict__ C, int N, int K) {
  __shared__ __align__(16) u16 lds[57344];
  int bx, by; swz_bid(bx, by);
  gemm256_body<192>(lds, A, B, C, N, K, by * 256, bx * 192, 1);
}

// ---------------- RoPE (in place, bf16) — K only ----------------
__global__ __launch_bounds__(256) void rope_kernel(u16* __restrict__ t, const float* __restrict__ fc,
                                                   const float* __restrict__ fs, int nheads, int total) {
  int idx = blockIdx.x * 256 + threadIdx.x;
  if (idx >= total) return;
  int c = idx & 7;
  int tmp = idx >> 3;
  int h = tmp % nheads;
  int row = tmp / nheads;
  int s = row & (S_LEN - 1);
  int d0 = c << 3;
  u16* base = t + (size_t)row * (nheads * 128) + h * 128;
  u16x8 lo = *(const u16x8*)(base + d0);
  u16x8 hi = *(const u16x8*)(base + 64 + d0);
  const float* cp = fc + s * 64 + d0;
  const float* sp = fs + s * 64 + d0;
  u16x8 olo, ohi;
#pragma unroll
  for (int j = 0; j < 8; ++j) {
    float cv = cp[j], sn = sp[j];
    float a = b2f(lo[j]), b = b2f(hi[j]);
    olo[j] = f2b(a * cv - b * sn);
    ohi[j] = f2b(b * cv + a * sn);
  }
  *(u16x8*)(base + d0) = olo;
  *(u16x8*)(base + 64 + d0) = ohi;
}

// ---------------- causal GQA flash attention — single-panel LPT blocks ----------------
// ids 0-767: one (qb,h,b) panel each (cost 2qb+2), dispatched qb-DESCENDING
// (LPT schedule — long panels first, short backfill). XCD pinning best-effort
// via id&7. ids 768+: wo f32->bf16 conversion blocks (backfill attn's tail;
// only consumer is the final O-projection). Inner structure = r11 (2 q-sets/
// wave, 4 waves, dbuf K/V^T global_load_lds, wave-local P LDS, defer-max).
__global__ __launch_bounds__(256, 2) void attn_kernel(const u16* __restrict__ xq,
                                                      const u16* __restrict__ xk,
                                                      const u16* __restrict__ xvT,
                                                      const float* __restrict__ fc,
                                                      const float* __restrict__ fs,
                                                      u16* __restrict__ o,
                                                      const float* __restrict__ wo,
                                                      u16* __restrict__ wob) {
  __shared__ __align__(16) u16 smem[40960];    // 80 KB: K dbuf 32K + V dbuf 32K + P 16K
  if (blockIdx.x >= 768) {                     // cvt(wo) backfill blocks
    int i = (blockIdx.x - 768) * 256 + threadIdx.x;   // 4608*256 = 1179648 exactly
    cvt_one(wo, wob, i);
    return;
  }
  const int tid = threadIdx.x;
  const int w = tid >> 6, lane = tid & 63;
  const int l15 = lane & 15, g = lane >> 4;
  const int id = blockIdx.x;
  const int xcd = id & 7, slot = id >> 3;      // slot in [0,96)
  const int grp = xcd + 8 * (slot / 48);       // (b,kvh) group, 0..15
  const int s48 = slot % 48;
  const int b = grp >> 3, kvh = grp & 7;
  const int qb = 15 - s48 / 3;                 // qb descending in dispatch order (LPT)
  const int h = kvh * 3 + s48 % 3;
  const float sc2 = 0.08838834764831845f * 1.4426950408889634f;  // 1/sqrt(128)*log2e

  const u16* ksrc = xk + (size_t)b * 2097152 + kvh * 128;          // [s][1024]
  const u16* vsrc = xvT + (size_t)(b * 1024 + kvh * 128) * 2048;   // [d][2048]
  int koff[4], vofs[4], dst4[4];
#pragma unroll
  for (int r = 0; r < 4; ++r) {
    int c = r * 256 + tid;
    int krow = c >> 4, kj = (c & 15) ^ (krow & 7);   // K: 64 rows x 16 chunks
    koff[r] = krow * 1024 + kj * 8;
    int vrow = c >> 3, vj = (c & 7) ^ (vrow & 7);    // V^T: 128 rows x 8 chunks
    vofs[r] = vrow * 2048 + vj * 8;
    dst4[r] = (r * 256 + (tid & 192)) * 8;           // wave-uniform LDS chunk base
  }
  u16* sPw = smem + 32768 + w * 2048;          // per-wave P: 2 sets x 1024 u16
  const int pxr = (l15 & 7) << 3;

  const int q0 = qb * 128;

  // Q load + fused RoPE + pre-scale, 2 sets
  bf16x8 qf[2][4];
#pragma unroll
  for (int s = 0; s < 2; ++s) {
    const int qrow = q0 + w * 32 + s * 16 + l15;
    const u16* qptr = xq + (size_t)(b * S_LEN + qrow) * DM + h * 128;
#pragma unroll
    for (int dcp = 0; dcp < 2; ++dcp) {
      u16x8 Lo = *(const u16x8*)(qptr + dcp * 32 + g * 8);
      u16x8 Hi = *(const u16x8*)(qptr + 64 + dcp * 32 + g * 8);
      const float* cp = fc + qrow * 64 + dcp * 32 + g * 8;
      const float* sp = fs + qrow * 64 + dcp * 32 + g * 8;
      bf16x8 qlo, qhi;
#pragma unroll
      for (int j = 0; j < 8; ++j) {
        float cv = cp[j], sn = sp[j];
        float a = b2f(Lo[j]), bb = b2f(Hi[j]);
        qlo[j] = (__bf16)((a * cv - bb * sn) * sc2);
        qhi[j] = (__bf16)((bb * cv + a * sn) * sc2);
      }
      qf[s][dcp] = qlo;
      qf[s][dcp + 2] = qhi;
    }
  }

  u16 *sKc = smem, *sKn = smem + 8192;
  u16 *sVc = smem + 16384, *sVn = smem + 24576;

  f32x4 accO[2][8];
#pragma unroll
  for (int s = 0; s < 2; ++s)
#pragma unroll
    for (int i = 0; i < 8; ++i) accO[s][i] = 0.f;
  float m_[2] = {-1e30f, -1e30f}, ls_[2] = {0.f, 0.f};
  const int nt = 2 * qb + 2;

#pragma unroll
  for (int r = 0; r < 4; ++r) gload16(ksrc + koff[r], sKc + dst4[r]);
#pragma unroll
  for (int r = 0; r < 4; ++r) gload16(vsrc + vofs[r], sVc + dst4[r]);
  __syncthreads();

  for (int t = 0; t < nt; ++t) {
    if (t + 1 < nt) {
      int k0n = (t + 1) * 64;
#pragma unroll
      for (int r = 0; r < 4; ++r) gload16(ksrc + (size_t)k0n * 1024 + koff[r], sKn + dst4[r]);
#pragma unroll
      for (int r = 0; r < 4; ++r) gload16(vsrc + k0n + vofs[r], sVn + dst4[r]);
    }
    if (64 * t <= q0 + w * 32 + 31) {           // wave-level causal skip
      // QK^T both sets: each kf read feeds 2 MFMAs
      f32x4 st[2][4];
      __builtin_amdgcn_s_setprio(1);
#pragma unroll
      for (int kt = 0; kt < 4; ++kt) {
        int row = kt * 16 + l15;
        bf16x8 kf[4];
#pragma unroll
        for (int dc = 0; dc < 4; ++dc)
          kf[dc] = *(const bf16x8*)(sKc + row * 128 + ((dc * 32 + g * 8) ^ ((row & 7) << 3)));
        f32x4 a0 = 0.f, a1 = 0.f;
#pragma unroll
        for (int dc = 0; dc < 4; ++dc) {
          a0 = mfma16(kf[dc], qf[0][dc], a0);
          a1 = mfma16(kf[dc], qf[1][dc], a1);
        }
        st[0][kt] = a0;
        st[1][kt] = a1;
      }
      __builtin_amdgcn_s_setprio(0);
      // softmax per set (mask, defer-max, exp2, P to wave-local LDS)
#pragma unroll
      for (int s = 0; s < 2; ++s) {
        const int qrow = q0 + w * 32 + s * 16 + l15;
        float pmax = -1e30f;
#pragma unroll
        for (int kt = 0; kt < 4; ++kt)
#pragma unroll
          for (int r = 0; r < 4; ++r) {
            float x = st[s][kt][r];
            if (t >= nt - 2) {
              int kk = t * 64 + kt * 16 + g * 4 + r;
              if (kk > qrow) x = -1e30f;
            }
            st[s][kt][r] = x;
            pmax = fmaxf(pmax, x);
          }
        pmax = fmaxf(pmax, __shfl_xor(pmax, 16));
        pmax = fmaxf(pmax, __shfl_xor(pmax, 32));
        if (!__all(pmax - m_[s] <= 8.0f)) {    // defer-max
          float mnew = fmaxf(m_[s], pmax);
          float corr = exp2f(m_[s] - mnew);
          ls_[s] *= corr;
#pragma unroll
          for (int i = 0; i < 8; ++i) accO[s][i] *= corr;
          m_[s] = mnew;
        }
        float ps = 0.f;
#pragma unroll
        for (int kt = 0; kt < 4; ++kt) {
          u16x4 pk;
#pragma unroll
          for (int r = 0; r < 4; ++r) {
            float p = exp2f(st[s][kt][r] - m_[s]);
            ps += p;
            pk[r] = f2b(p);
          }
          *(u16x4*)(sPw + s * 1024 + ((l15 * 64 + kt * 16 + g * 4) ^ pxr)) = pk;
        }
        ps += __shfl_xor(ps, 16);
        ps += __shfl_xor(ps, 32);
        ls_[s] += ps;
      }
      // P fragments (wave-local LDS)
      bf16x8 pf[2][2];
#pragma unroll
      for (int s = 0; s < 2; ++s)
#pragma unroll
        for (int ck = 0; ck < 2; ++ck)
          pf[s][ck] = *(const bf16x8*)(sPw + s * 1024 + ((l15 * 64 + ck * 32 + g * 8) ^ pxr));
      // PV both sets: each vf read feeds 2 MFMAs
      __builtin_amdgcn_s_setprio(1);
#pragma unroll
      for (int dt = 0; dt < 8; ++dt) {
        int row = dt * 16 + l15;
#pragma unroll
        for (int ck = 0; ck < 2; ++ck) {
          bf16x8 vf = *(const bf16x8*)(sVc + row * 64 + ((ck * 32 + g * 8) ^ ((row & 7) << 3)));
          accO[0][dt] = mfma16(vf, pf[0][ck], accO[0][dt]);
          accO[1][dt] = mfma16(vf, pf[1][ck], accO[1][dt]);
        }
      }
      __builtin_amdgcn_s_setprio(0);
    }
    __syncthreads();                            // drains stage vmcnt + cur reads done
    u16* tk = sKc; sKc = sKn; sKn = tk;
    u16* tv = sVc; sVc = sVn; sVn = tv;
  }
  // epilogue: per-wave [32 q][128 d] transpose in (dead) K/V LDS region
  u16* sOw = smem + w * 8192;
#pragma unroll
  for (int s = 0; s < 2; ++s) {
    float invl = 1.0f / ls_[s];
#pragma unroll
    for (int dt = 0; dt < 8; ++dt)
#pragma unroll
      for (int r = 0; r < 4; ++r) {
        int d = dt * 16 + g * 4 + r;
        sOw[((s * 16 + l15) * 128 + d) ^ pxr] = f2b(accO[s][dt][r] * invl);
      }
  }
#pragma unroll
  for (int p = 0; p < 8; ++p) {
    int idx = p * 64 + lane;
    int q = idx >> 4, c = idx & 15;
    int j = c ^ (q & 7);
    u32x4 v = *(const u32x4*)(sOw + q * 128 + j * 8);
    *(u32x4*)(o + (size_t)(b * S_LEN + q0 + w * 32 + q) * DM + h * 128 + c * 8) = v;
  }
}

// ---------------- launch ----------------
extern "C" void kernel_launch(void* const* d_in, const int* in_sizes, int n_in,
                              void* d_out, int out_size, void* d_ws, size_t ws_size,
                              hipStream_t stream) {
  const float* x  = (const float*)d_in[0];
  const float* fc = (const float*)d_in[1];
  const float* fs = (const float*)d_in[2];
  const float* wq = (const float*)d_in[4];
  const float* wk = (const float*)d_in[5];
  const float* wv = (const float*)d_in[6];
  const float* wo = (const float*)d_in[7];
  float* out = (float*)d_out;
  char* ws = (char*)d_ws;

  u16* xb  = (u16*)(ws);                 // x bf16      25,165,824
  u16* wqb = (u16*)(ws + 25165824);      // wq bf16     18,874,368
  u16* att = (u16*)(ws + 25165824);      // attn out (aliases wq/wk after death)
  u16* wkb = (u16*)(ws + 44040192);      // wk bf16      6,291,456
  u16* wvb = (u16*)(ws + 50331648);      // wv bf16      6,291,456
  u16* xqb = (u16*)(ws + 56623104);      // xq bf16     25,165,824
  u16* xkb = (u16*)(ws + 81788928);      // xk bf16      8,388,608
  u16* xvT = (u16*)(ws + 90177536);      // V^T bf16     8,388,608
  u16* wob = (u16*)(ws);                 // wo bf16 (aliases xb, dead after gemm_qkv)

  cvt4_kernel<<<13824, 256, 0, stream>>>(x, xb, wq, wqb, wk, wkb, wv, wvb);

  gemm_qkv<<<512, 512, 0, stream>>>(xb, wqb, xqb, wkb, wvb, xkb, xvT, 3072);

  rope_kernel<<<1024, 256, 0, stream>>>(xkb, fc, fs, NKV, 4096 * NKV * 8);  // K only

  attn_kernel<<<5376, 256, 0, stream>>>(xqb, xkb, xvT, fc, fs, att, wo, wob);

  gemm192_f32<<<dim3(16, 16), 512, 0, stream>>>(att, wob, out, 3072, 3072);
}

// Round 13
// 328.624 us; speedup vs baseline: 2.3245x; 1.0389x over previous
//
#include <hip/hip_runtime.h>

typedef unsigned short u16;
typedef unsigned int u32;
typedef __attribute__((ext_vector_type(8))) __bf16 bf16x8;
typedef __attribute__((ext_vector_type(4))) float f32x4;
typedef __attribute__((ext_vector_type(4))) u32 u32x4;
typedef __attribute__((ext_vector_type(8))) u16 u16x8;
typedef __attribute__((ext_vector_type(4))) u16 u16x4;

#define S_LEN 2048
#define DM 3072
#define NH 24
#define NKV 8

__device__ __forceinline__ u16 f2b(float f) {
  u32 u = __builtin_bit_cast(u32, f);
  u = u + 0x7FFFu + ((u >> 16) & 1u);
  return (u16)(u >> 16);
}
__device__ __forceinline__ float b2f(u16 h) {
  u32 u = ((u32)h) << 16;
  return __builtin_bit_cast(float, u);
}
__device__ __forceinline__ f32x4 mfma16(bf16x8 a, bf16x8 b, f32x4 c) {
  return __builtin_amdgcn_mfma_f32_16x16x32_bf16(a, b, c, 0, 0, 0);
}
__device__ __forceinline__ void gload16(const u16* g, u16* l) {
  __builtin_amdgcn_global_load_lds((const __attribute__((address_space(1))) void*)g,
                                   (__attribute__((address_space(3))) void*)l, 16, 0, 0);
}

// ---------------- f32 -> bf16 conversion ----------------
__device__ __forceinline__ void cvt_one(const float* __restrict__ s, u16* __restrict__ d, int j) {
  const f32x4* p = (const f32x4*)(s + (size_t)j * 8);
  f32x4 a = p[0], b = p[1];
  u16x8 o;
#pragma unroll
  for (int q = 0; q < 4; ++q) { o[q] = f2b(a[q]); o[q + 4] = f2b(b[q]); }
  *(u16x8*)(d + (size_t)j * 8) = o;
}
__global__ __launch_bounds__(256) void cvt4_kernel(const float* __restrict__ s0, u16* __restrict__ d0,
                                                   const float* __restrict__ s1, u16* __restrict__ d1,
                                                   const float* __restrict__ s2, u16* __restrict__ d2,
                                                   const float* __restrict__ s3, u16* __restrict__ d3) {
  int i = blockIdx.x * 256 + threadIdx.x;
  if (i < 1572864)      cvt_one(s0, d0, i);
  else if (i < 2752512) cvt_one(s1, d1, i - 1572864);
  else if (i < 3145728) cvt_one(s2, d2, i - 2752512);
  else                  cvt_one(s3, d3, i - 3145728);
}

// ---------------- XCD-aware block swizzle ----------------
__device__ __forceinline__ void swz_bid(int& bx, int& by) {
  int gx = gridDim.x;
  int tot = gx * gridDim.y;          // must be divisible by 8
  int id = blockIdx.y * gx + blockIdx.x;
  int cpx = tot >> 3;
  int s = (id & 7) * cpx + (id >> 3);
  bx = s % gx;
  by = s / gx;
}

// ---------------- phase-interleaved GEMM body (LDS passed in) ----------------
// C[m,n] = sum_k A[m,k]*B[n,k], row-major over K (K=3072, 48 K-tiles of 64).
// BM=256, BN in {320,192,128}; 512 threads = 8 waves (2M x 4N). LDS rows linear,
// chunk^(row&7) swizzle, pre-swizzled sources. 4 phases/K-tile.
// modes: 0 bf16, 1 f32, 2 V^T bf16, 3 QKV-concat routing (Cv=xq, C2=xk, C3=xvT;
// B is the concatenated 5120x3072 weight, col nn<3072 -> Q, <4096 -> K, else V^T).
// LDS requirement: 32768 + 2*BN*64 u16.
template <int BN>
__device__ __forceinline__ void gemm256_body(u16* __restrict__ lds,
                                             const u16* __restrict__ A, const u16* __restrict__ B,
                                             void* __restrict__ Cv, int N, int K,
                                             int m0, int n0, int mode,
                                             void* __restrict__ C2 = nullptr,
                                             void* __restrict__ C3 = nullptr) {
  constexpr int NJ = BN / 64;
  constexpr int NSB = BN / 64;
  constexpr int BBUF = NSB * 4096;
  const int tid = threadIdx.x;
  const int lane = tid & 63;
  const int w = tid >> 6;
  const int l15 = lane & 15, g = lane >> 4;
  const int wm = w >> 2, wn = w & 3;
  const int srow = tid >> 3;
  const int scol = ((tid & 7) ^ (srow & 7)) * 8;
  const u16* aS = A + (size_t)(m0 + srow) * K + scol;
  const u16* bS = B + (size_t)(n0 + srow) * K + scol;
  const int sdst = (tid & 448) * 8;
  const int swz0 = (g ^ (l15 & 7)) * 8;
  const int swz1 = ((4 + g) ^ (l15 & 7)) * 8;
  const int aB0 = wm * 8192 + l15 * 64;
  const int bB0 = wn * (BN / 4) * 64 + l15 * 64;

  f32x4 acc[8][NJ];
#pragma unroll
  for (int i = 0; i < 8; ++i)
#pragma unroll
    for (int j = 0; j < NJ; ++j) acc[i][j] = 0.f;

  auto stage = [&](int k0, int bsel) {
#pragma unroll
    for (int s = 0; s < 4; ++s)
      gload16(aS + (size_t)(s * 64) * K + k0, lds + bsel * 16384 + s * 4096 + sdst);
#pragma unroll
    for (int s = 0; s < NSB; ++s)
      gload16(bS + (size_t)(s * 64) * K + k0, lds + 32768 + bsel * BBUF + s * 4096 + sdst);
  };

  stage(0, 0);
  asm volatile("s_waitcnt vmcnt(0)" ::: "memory");
  __builtin_amdgcn_s_barrier();

  for (int t = 0; t < 48; ++t) {
    const int bsel = t & 1;
    const u16* ldsA = lds + bsel * 16384 + aB0;
    const u16* ldsB = lds + 32768 + bsel * BBUF + bB0;
    bf16x8 af[4], bf[NJ];
    // ---- P0: kh0, mi 0-3 (+ stage next tile)
#pragma unroll
    for (int i = 0; i < 4; ++i) af[i] = *(const bf16x8*)(ldsA + i * 1024 + swz0);
#pragma unroll
    for (int j = 0; j < NJ; ++j) bf[j] = *(const bf16x8*)(ldsB + j * 1024 + swz0);
    if (t < 47) stage((t + 1) * 64, bsel ^ 1);
    asm volatile("" ::: "memory");
    __builtin_amdgcn_s_barrier();
    asm volatile("s_waitcnt lgkmcnt(0)" ::: "memory");
    __builtin_amdgcn_sched_barrier(0);
    __builtin_amdgcn_s_setprio(1);
#pragma unroll
    for (int i = 0; i < 4; ++i)
#pragma unroll
      for (int j = 0; j < NJ; ++j) acc[i][j] = mfma16(af[i], bf[j], acc[i][j]);
    __builtin_amdgcn_s_setprio(0);
    asm volatile("" ::: "memory");
    __builtin_amdgcn_s_barrier();
    // ---- P1: kh0, mi 4-7
#pragma unroll
    for (int i = 0; i < 4; ++i) af[i] = *(const bf16x8*)(ldsA + (4 + i) * 1024 + swz0);
    asm volatile("" ::: "memory");
    __builtin_amdgcn_s_barrier();
    asm volatile("s_waitcnt lgkmcnt(0)" ::: "memory");
    __builtin_amdgcn_sched_barrier(0);
    __builtin_amdgcn_s_setprio(1);
#pragma unroll
    for (int i = 0; i < 4; ++i)
#pragma unroll
      for (int j = 0; j < NJ; ++j) acc[4 + i][j] = mfma16(af[i], bf[j], acc[4 + i][j]);
    __builtin_amdgcn_s_setprio(0);
    asm volatile("" ::: "memory");
    __builtin_amdgcn_s_barrier();
    // ---- P2: kh1, mi 0-3
#pragma unroll
    for (int i = 0; i < 4; ++i) af[i] = *(const bf16x8*)(ldsA + i * 1024 + swz1);
#pragma unroll
    for (int j = 0; j < NJ; ++j) bf[j] = *(const bf16x8*)(ldsB + j * 1024 + swz1);
    asm volatile("" ::: "memory");
    __builtin_amdgcn_s_barrier();
    asm volatile("s_waitcnt lgkmcnt(0)" ::: "memory");
    __builtin_amdgcn_sched_barrier(0);
    __builtin_amdgcn_s_setprio(1);
#pragma unroll
    for (int i = 0; i < 4; ++i)
#pragma unroll
      for (int j = 0; j < NJ; ++j) acc[i][j] = mfma16(af[i], bf[j], acc[i][j]);
    __builtin_amdgcn_s_setprio(0);
    asm volatile("" ::: "memory");
    __builtin_amdgcn_s_barrier();
    // ---- P3: kh1, mi 4-7 (+ drain for next tile's buffer)
#pragma unroll
    for (int i = 0; i < 4; ++i) af[i] = *(const bf16x8*)(ldsA + (4 + i) * 1024 + swz1);
    asm volatile("" ::: "memory");
    asm volatile("s_waitcnt vmcnt(0)" ::: "memory");
    __builtin_amdgcn_s_barrier();
    asm volatile("s_waitcnt lgkmcnt(0)" ::: "memory");
    __builtin_amdgcn_sched_barrier(0);
    __builtin_amdgcn_s_setprio(1);
#pragma unroll
    for (int i = 0; i < 4; ++i)
#pragma unroll
      for (int j = 0; j < NJ; ++j) acc[4 + i][j] = mfma16(af[i], bf[j], acc[4 + i][j]);
    __builtin_amdgcn_s_setprio(0);
    asm volatile("" ::: "memory");
    __builtin_amdgcn_s_barrier();
  }
  // ---- epilogue
#pragma unroll
  for (int i = 0; i < 8; ++i)
#pragma unroll
    for (int j = 0; j < NJ; ++j) {
      int nn = n0 + wn * (BN / 4) + j * 16 + l15;
      int mmb = m0 + wm * 128 + i * 16 + g * 4;
      if (mode == 1) {
#pragma unroll
        for (int r = 0; r < 4; ++r)
          ((float*)Cv)[(size_t)(mmb + r) * N + nn] = acc[i][j][r];
      } else if (mode == 0) {
#pragma unroll
        for (int r = 0; r < 4; ++r)
          ((u16*)Cv)[(size_t)(mmb + r) * N + nn] = f2b(acc[i][j][r]);
      } else if (mode == 2) {
        u16x4 pk;
#pragma unroll
        for (int r = 0; r < 4; ++r) pk[r] = f2b(acc[i][j][r]);
        *(u16x4*)((u16*)Cv + (size_t)nn * 2048 + (size_t)(mmb >> 11) * 2097152 + (mmb & 2047)) = pk;
      } else {                                 // mode 3: QKV concat routing
        if (nn < 3072) {
#pragma unroll
          for (int r = 0; r < 4; ++r)
            ((u16*)Cv)[(size_t)(mmb + r) * 3072 + nn] = f2b(acc[i][j][r]);
        } else if (nn < 4096) {
#pragma unroll
          for (int r = 0; r < 4; ++r)
            ((u16*)C2)[(size_t)(mmb + r) * 1024 + (nn - 3072)] = f2b(acc[i][j][r]);
        } else {
          int d = nn - 4096;
          u16x4 pk;
#pragma unroll
          for (int r = 0; r < 4; ++r) pk[r] = f2b(acc[i][j][r]);
          *(u16x4*)((u16*)C3 + (size_t)d * 2048 + (size_t)(mmb >> 11) * 2097152 + (mmb & 2047)) = pk;
        }
      }
    }
}

// merged QKV projection: B = concatenated [wq;wk;wv] (5120x3072, contiguous in ws).
// grid 256 = 16 row-panels x 16 col-tiles of 320 -> exactly one full machine round.
__global__ __launch_bounds__(512, 1) void gemm_qkv(const u16* __restrict__ A,
                                                   const u16* __restrict__ Wcat,
                                                   u16* __restrict__ Cq,
                                                   u16* __restrict__ Ck, u16* __restrict__ Cv,
                                                   int K) {
  __shared__ __align__(16) u16 lds[73728];     // 144 KB
  int id = blockIdx.x;
  int s = (id & 7) * 32 + (id >> 3);           // XCD-chunked
  int by = s >> 4, c = s & 15;
  gemm256_body<320>(lds, A, Wcat, Cq, 0, K, by * 256, c * 320, 3, Ck, Cv);
}
// O-projection (f32 out), grid (16,16)
__global__ __launch_bounds__(512, 1) void gemm192_f32(const u16* __restrict__ A, const u16* __restrict__ B,
                                                      float* __restrict__ C, int N, int K) {
  __shared__ __align__(16) u16 lds[57344];
  int bx, by; swz_bid(bx, by);
  gemm256_body<192>(lds, A, B, C, N, K, by * 256, bx * 192, 1);
}

// ---------------- RoPE (in place, bf16) — K only ----------------
__global__ __launch_bounds__(256) void rope_kernel(u16* __restrict__ t, const float* __restrict__ fc,
                                                   const float* __restrict__ fs, int nheads, int total) {
  int idx = blockIdx.x * 256 + threadIdx.x;
  if (idx >= total) return;
  int c = idx & 7;
  int tmp = idx >> 3;
  int h = tmp % nheads;
  int row = tmp / nheads;
  int s = row & (S_LEN - 1);
  int d0 = c << 3;
  u16* base = t + (size_t)row * (nheads * 128) + h * 128;
  u16x8 lo = *(const u16x8*)(base + d0);
  u16x8 hi = *(const u16x8*)(base + 64 + d0);
  const float* cp = fc + s * 64 + d0;
  const float* sp = fs + s * 64 + d0;
  u16x8 olo, ohi;
#pragma unroll
  for (int j = 0; j < 8; ++j) {
    float cv = cp[j], sn = sp[j];
    float a = b2f(lo[j]), b = b2f(hi[j]);
    olo[j] = f2b(a * cv - b * sn);
    ohi[j] = f2b(b * cv + a * sn);
  }
  *(u16x8*)(base + d0) = olo;
  *(u16x8*)(base + 64 + d0) = ohi;
}

// ---------------- causal GQA flash attention — single-panel LPT blocks ----------------
// ids 0-767: one (qb,h,b) panel each (cost 2qb+2), qb-descending (LPT). XCD
// pinning best-effort via id&7. ids 768+: wo f32->bf16 conversion backfill.
// Inner: r11 (2 q-sets/wave, 4 waves, dbuf K/V^T global_load_lds, wave-local
// P LDS, defer-max, exp2 softmax, fused Q-RoPE).
__global__ __launch_bounds__(256, 2) void attn_kernel(const u16* __restrict__ xq,
                                                      const u16* __restrict__ xk,
                                                      const u16* __restrict__ xvT,
                                                      const float* __restrict__ fc,
                                                      const float* __restrict__ fs,
                                                      u16* __restrict__ o,
                                                      const float* __restrict__ wo,
                                                      u16* __restrict__ wob) {
  __shared__ __align__(16) u16 smem[40960];    // 80 KB: K dbuf 32K + V dbuf 32K + P 16K
  if (blockIdx.x >= 768) {                     // cvt(wo) backfill blocks
    int i = (blockIdx.x - 768) * 256 + threadIdx.x;   // 4608*256 = 1179648 exactly
    cvt_one(wo, wob, i);
    return;
  }
  const int tid = threadIdx.x;
  const int w = tid >> 6, lane = tid & 63;
  const int l15 = lane & 15, g = lane >> 4;
  const int id = blockIdx.x;
  const int xcd = id & 7, slot = id >> 3;      // slot in [0,96)
  const int grp = xcd + 8 * (slot / 48);       // (b,kvh) group, 0..15
  const int s48 = slot % 48;
  const int b = grp >> 3, kvh = grp & 7;
  const int qb = 15 - s48 / 3;                 // qb descending (LPT)
  const int h = kvh * 3 + s48 % 3;
  const float sc2 = 0.08838834764831845f * 1.4426950408889634f;  // 1/sqrt(128)*log2e

  const u16* ksrc = xk + (size_t)b * 2097152 + kvh * 128;          // [s][1024]
  const u16* vsrc = xvT + (size_t)(b * 1024 + kvh * 128) * 2048;   // [d][2048]
  int koff[4], vofs[4], dst4[4];
#pragma unroll
  for (int r = 0; r < 4; ++r) {
    int c = r * 256 + tid;
    int krow = c >> 4, kj = (c & 15) ^ (krow & 7);   // K: 64 rows x 16 chunks
    koff[r] = krow * 1024 + kj * 8;
    int vrow = c >> 3, vj = (c & 7) ^ (vrow & 7);    // V^T: 128 rows x 8 chunks
    vofs[r] = vrow * 2048 + vj * 8;
    dst4[r] = (r * 256 + (tid & 192)) * 8;           // wave-uniform LDS chunk base
  }
  u16* sPw = smem + 32768 + w * 2048;          // per-wave P: 2 sets x 1024 u16
  const int pxr = (l15 & 7) << 3;

  const int q0 = qb * 128;

  // Q load + fused RoPE + pre-scale, 2 sets
  bf16x8 qf[2][4];
#pragma unroll
  for (int s = 0; s < 2; ++s) {
    const int qrow = q0 + w * 32 + s * 16 + l15;
    const u16* qptr = xq + (size_t)(b * S_LEN + qrow) * DM + h * 128;
#pragma unroll
    for (int dcp = 0; dcp < 2; ++dcp) {
      u16x8 Lo = *(const u16x8*)(qptr + dcp * 32 + g * 8);
      u16x8 Hi = *(const u16x8*)(qptr + 64 + dcp * 32 + g * 8);
      const float* cp = fc + qrow * 64 + dcp * 32 + g * 8;
      const float* sp = fs + qrow * 64 + dcp * 32 + g * 8;
      bf16x8 qlo, qhi;
#pragma unroll
      for (int j = 0; j < 8; ++j) {
        float cv = cp[j], sn = sp[j];
        float a = b2f(Lo[j]), bb = b2f(Hi[j]);
        qlo[j] = (__bf16)((a * cv - bb * sn) * sc2);
        qhi[j] = (__bf16)((bb * cv + a * sn) * sc2);
      }
      qf[s][dcp] = qlo;
      qf[s][dcp + 2] = qhi;
    }
  }

  u16 *sKc = smem, *sKn = smem + 8192;
  u16 *sVc = smem + 16384, *sVn = smem + 24576;

  f32x4 accO[2][8];
#pragma unroll
  for (int s = 0; s < 2; ++s)
#pragma unroll
    for (int i = 0; i < 8; ++i) accO[s][i] = 0.f;
  float m_[2] = {-1e30f, -1e30f}, ls_[2] = {0.f, 0.f};
  const int nt = 2 * qb + 2;

#pragma unroll
  for (int r = 0; r < 4; ++r) gload16(ksrc + koff[r], sKc + dst4[r]);
#pragma unroll
  for (int r = 0; r < 4; ++r) gload16(vsrc + vofs[r], sVc + dst4[r]);
  __syncthreads();

  for (int t = 0; t < nt; ++t) {
    if (t + 1 < nt) {
      int k0n = (t + 1) * 64;
#pragma unroll
      for (int r = 0; r < 4; ++r) gload16(ksrc + (size_t)k0n * 1024 + koff[r], sKn + dst4[r]);
#pragma unroll
      for (int r = 0; r < 4; ++r) gload16(vsrc + k0n + vofs[r], sVn + dst4[r]);
    }
    if (64 * t <= q0 + w * 32 + 31) {           // wave-level causal skip
      // QK^T both sets: each kf read feeds 2 MFMAs
      f32x4 st[2][4];
      __builtin_amdgcn_s_setprio(1);
#pragma unroll
      for (int kt = 0; kt < 4; ++kt) {
        int row = kt * 16 + l15;
        bf16x8 kf[4];
#pragma unroll
        for (int dc = 0; dc < 4; ++dc)
          kf[dc] = *(const bf16x8*)(sKc + row * 128 + ((dc * 32 + g * 8) ^ ((row & 7) << 3)));
        f32x4 a0 = 0.f, a1 = 0.f;
#pragma unroll
        for (int dc = 0; dc < 4; ++dc) {
          a0 = mfma16(kf[dc], qf[0][dc], a0);
          a1 = mfma16(kf[dc], qf[1][dc], a1);
        }
        st[0][kt] = a0;
        st[1][kt] = a1;
      }
      __builtin_amdgcn_s_setprio(0);
      // softmax per set (mask, defer-max, exp2, P to wave-local LDS)
#pragma unroll
      for (int s = 0; s < 2; ++s) {
        const int qrow = q0 + w * 32 + s * 16 + l15;
        float pmax = -1e30f;
#pragma unroll
        for (int kt = 0; kt < 4; ++kt)
#pragma unroll
          for (int r = 0; r < 4; ++r) {
            float x = st[s][kt][r];
            if (t >= nt - 2) {
              int kk = t * 64 + kt * 16 + g * 4 + r;
              if (kk > qrow) x = -1e30f;
            }
            st[s][kt][r] = x;
            pmax = fmaxf(pmax, x);
          }
        pmax = fmaxf(pmax, __shfl_xor(pmax, 16));
        pmax = fmaxf(pmax, __shfl_xor(pmax, 32));
        if (!__all(pmax - m_[s] <= 8.0f)) {    // defer-max
          float mnew = fmaxf(m_[s], pmax);
          float corr = exp2f(m_[s] - mnew);
          ls_[s] *= corr;
#pragma unroll
          for (int i = 0; i < 8; ++i) accO[s][i] *= corr;
          m_[s] = mnew;
        }
        float ps = 0.f;
#pragma unroll
        for (int kt = 0; kt < 4; ++kt) {
          u16x4 pk;
#pragma unroll
          for (int r = 0; r < 4; ++r) {
            float p = exp2f(st[s][kt][r] - m_[s]);
            ps += p;
            pk[r] = f2b(p);
          }
          *(u16x4*)(sPw + s * 1024 + ((l15 * 64 + kt * 16 + g * 4) ^ pxr)) = pk;
        }
        ps += __shfl_xor(ps, 16);
        ps += __shfl_xor(ps, 32);
        ls_[s] += ps;
      }
      // P fragments (wave-local LDS)
      bf16x8 pf[2][2];
#pragma unroll
      for (int s = 0; s < 2; ++s)
#pragma unroll
        for (int ck = 0; ck < 2; ++ck)
          pf[s][ck] = *(const bf16x8*)(sPw + s * 1024 + ((l15 * 64 + ck * 32 + g * 8) ^ pxr));
      // PV both sets: each vf read feeds 2 MFMAs
      __builtin_amdgcn_s_setprio(1);
#pragma unroll
      for (int dt = 0; dt < 8; ++dt) {
        int row = dt * 16 + l15;
#pragma unroll
        for (int ck = 0; ck < 2; ++ck) {
          bf16x8 vf = *(const bf16x8*)(sVc + row * 64 + ((ck * 32 + g * 8) ^ ((row & 7) << 3)));
          accO[0][dt] = mfma16(vf, pf[0][ck], accO[0][dt]);
          accO[1][dt] = mfma16(vf, pf[1][ck], accO[1][dt]);
        }
      }
      __builtin_amdgcn_s_setprio(0);
    }
    __syncthreads();                            // drains stage vmcnt + cur reads done
    u16* tk = sKc; sKc = sKn; sKn = tk;
    u16* tv = sVc; sVc = sVn; sVn = tv;
  }
  // epilogue: per-wave [32 q][128 d] transpose in (dead) K/V LDS region
  u16* sOw = smem + w * 8192;
#pragma unroll
  for (int s = 0; s < 2; ++s) {
    float invl = 1.0f / ls_[s];
#pragma unroll
    for (int dt = 0; dt < 8; ++dt)
#pragma unroll
      for (int r = 0; r < 4; ++r) {
        int d = dt * 16 + g * 4 + r;
        sOw[((s * 16 + l15) * 128 + d) ^ pxr] = f2b(accO[s][dt][r] * invl);
      }
  }
#pragma unroll
  for (int p = 0; p < 8; ++p) {
    int idx = p * 64 + lane;
    int q = idx >> 4, c = idx & 15;
    int j = c ^ (q & 7);
    u32x4 v = *(const u32x4*)(sOw + q * 128 + j * 8);
    *(u32x4*)(o + (size_t)(b * S_LEN + q0 + w * 32 + q) * DM + h * 128 + c * 8) = v;
  }
}

// ---------------- launch ----------------
extern "C" void kernel_launch(void* const* d_in, const int* in_sizes, int n_in,
                              void* d_out, int out_size, void* d_ws, size_t ws_size,
                              hipStream_t stream) {
  const float* x  = (const float*)d_in[0];
  const float* fc = (const float*)d_in[1];
  const float* fs = (const float*)d_in[2];
  const float* wq = (const float*)d_in[4];
  const float* wk = (const float*)d_in[5];
  const float* wv = (const float*)d_in[6];
  const float* wo = (const float*)d_in[7];
  float* out = (float*)d_out;
  char* ws = (char*)d_ws;

  u16* xb  = (u16*)(ws);                 // x bf16      25,165,824
  u16* wqb = (u16*)(ws + 25165824);      // wq bf16     18,874,368 ┐ contiguous = Wcat
  u16* att = (u16*)(ws + 25165824);      // attn out (aliases wq/wk after death)
  u16* wkb = (u16*)(ws + 44040192);      // wk bf16      6,291,456 │ (5120 x 3072)
  u16* wvb = (u16*)(ws + 50331648);      // wv bf16      6,291,456 ┘
  u16* xqb = (u16*)(ws + 56623104);      // xq bf16     25,165,824
  u16* xkb = (u16*)(ws + 81788928);      // xk bf16      8,388,608
  u16* xvT = (u16*)(ws + 90177536);      // V^T bf16     8,388,608
  u16* wob = (u16*)(ws);                 // wo bf16 (aliases xb, dead after gemm_qkv)

  cvt4_kernel<<<13824, 256, 0, stream>>>(x, xb, wq, wqb, wk, wkb, wv, wvb);

  gemm_qkv<<<256, 512, 0, stream>>>(xb, wqb, xqb, xkb, xvT, 3072);

  rope_kernel<<<1024, 256, 0, stream>>>(xkb, fc, fs, NKV, 4096 * NKV * 8);  // K only

  attn_kernel<<<5376, 256, 0, stream>>>(xqb, xkb, xvT, fc, fs, att, wo, wob);

  gemm192_f32<<<dim3(16, 16), 512, 0, stream>>>(att, wob, out, 3072, 3072);
}

// Round 14
// 313.523 us; speedup vs baseline: 2.4364x; 1.0482x over previous
//
#include <hip/hip_runtime.h>

typedef unsigned short u16;
typedef unsigned int u32;
typedef __attribute__((ext_vector_type(8))) __bf16 bf16x8;
typedef __attribute__((ext_vector_type(4))) float f32x4;
typedef __attribute__((ext_vector_type(4))) u32 u32x4;
typedef __attribute__((ext_vector_type(8))) u16 u16x8;
typedef __attribute__((ext_vector_type(4))) u16 u16x4;

#define S_LEN 2048
#define DM 3072
#define NH 24
#define NKV 8

#define WAITV(n) asm volatile("s_waitcnt vmcnt(" #n ")" ::: "memory")

__device__ __forceinline__ u16 f2b(float f) {
  u32 u = __builtin_bit_cast(u32, f);
  u = u + 0x7FFFu + ((u >> 16) & 1u);
  return (u16)(u >> 16);
}
__device__ __forceinline__ float b2f(u16 h) {
  u32 u = ((u32)h) << 16;
  return __builtin_bit_cast(float, u);
}
__device__ __forceinline__ f32x4 mfma16(bf16x8 a, bf16x8 b, f32x4 c) {
  return __builtin_amdgcn_mfma_f32_16x16x32_bf16(a, b, c, 0, 0, 0);
}
__device__ __forceinline__ void gload16(const u16* g, u16* l) {
  __builtin_amdgcn_global_load_lds((const __attribute__((address_space(1))) void*)g,
                                   (__attribute__((address_space(3))) void*)l, 16, 0, 0);
}

// ---------------- f32 -> bf16 conversion ----------------
__device__ __forceinline__ void cvt_one(const float* __restrict__ s, u16* __restrict__ d, int j) {
  const f32x4* p = (const f32x4*)(s + (size_t)j * 8);
  f32x4 a = p[0], b = p[1];
  u16x8 o;
#pragma unroll
  for (int q = 0; q < 4; ++q) { o[q] = f2b(a[q]); o[q + 4] = f2b(b[q]); }
  *(u16x8*)(d + (size_t)j * 8) = o;
}
__global__ __launch_bounds__(256) void cvt4_kernel(const float* __restrict__ s0, u16* __restrict__ d0,
                                                   const float* __restrict__ s1, u16* __restrict__ d1,
                                                   const float* __restrict__ s2, u16* __restrict__ d2,
                                                   const float* __restrict__ s3, u16* __restrict__ d3) {
  int i = blockIdx.x * 256 + threadIdx.x;
  if (i < 1572864)      cvt_one(s0, d0, i);
  else if (i < 2752512) cvt_one(s1, d1, i - 1572864);
  else if (i < 3145728) cvt_one(s2, d2, i - 2752512);
  else                  cvt_one(s3, d3, i - 3145728);
}

// ---------------- XCD-aware block swizzle ----------------
__device__ __forceinline__ void swz_bid(int& bx, int& by) {
  int gx = gridDim.x;
  int tot = gx * gridDim.y;          // must be divisible by 8
  int id = blockIdx.y * gx + blockIdx.x;
  int cpx = tot >> 3;
  int s = (id & 7) * cpx + (id >> 3);
  bx = s % gx;
  by = s / gx;
}

// ---------------- counted-vmcnt phase-interleaved GEMM (T4) ----------------
// C[m,n] = sum_k A[m,k]*B[n,k], row-major over K (K=3072, 48 K-tiles of 64).
// BM=256, BN in {320,192}; 512 threads = 8 waves (2M x 4N). bf[j] is slot-aligned:
// rows j*64 + wn*16 + l15 (stage slot j = 64 rows = 1 gload16/thread).
// Staggered staging (P0:A, P1:B01, P2:B23, P3:B4) + counted waits vmcnt(4)@P0 /
// vmcnt(NJ-2)@P3 -- loads stay in flight across barriers (never drain to 0 in
// steady state; m218's lever). 2 barriers/phase. LDS chunk^(row&7) swizzle with
// pre-swizzled global sources. modes: 0 bf16, 1 f32, 2 V^T bf16, 3 QKV routing.
template <int BN>
__device__ __forceinline__ void gemm256_body(u16* __restrict__ lds,
                                             const u16* __restrict__ A, const u16* __restrict__ B,
                                             void* __restrict__ Cv, int N, int K,
                                             int m0, int n0, int mode,
                                             void* __restrict__ C2 = nullptr,
                                             void* __restrict__ C3 = nullptr) {
  constexpr int NJ = BN / 64;                  // B slots / per-wave n-frags (5 or 3)
  constexpr int BBUF = NJ * 4096;              // B u16 per buffer
  const int tid = threadIdx.x;
  const int lane = tid & 63;
  const int w = tid >> 6;
  const int l15 = lane & 15, g = lane >> 4;
  const int wm = w >> 2, wn = w & 3;
  const int srow = tid >> 3;
  const int scol = ((tid & 7) ^ (srow & 7)) * 8;
  const u16* aS = A + (size_t)(m0 + srow) * K + scol;
  const u16* bS = B + (size_t)(n0 + srow) * K + scol;
  const int sdst = (tid & 448) * 8;
  const int swz0 = (g ^ (l15 & 7)) * 8;
  const int swz1 = ((4 + g) ^ (l15 & 7)) * 8;
  const int aB0 = wm * 8192 + l15 * 64;
  const int bB0 = wn * 1024 + l15 * 64;        // within-slot row = wn*16 + l15

  f32x4 acc[8][NJ];
#pragma unroll
  for (int i = 0; i < 8; ++i)
#pragma unroll
    for (int j = 0; j < NJ; ++j) acc[i][j] = 0.f;

  auto stgA = [&](int k0, int bsel) {
#pragma unroll
    for (int s = 0; s < 4; ++s)
      gload16(aS + (size_t)(s * 64) * K + k0, lds + bsel * 16384 + s * 4096 + sdst);
  };
  auto stgB = [&](int k0, int bsel, int s) {
    gload16(bS + (size_t)(s * 64) * K + k0, lds + 32768 + bsel * BBUF + s * 4096 + sdst);
  };

  // prologue: tile 0 (A, then B slots ascending), retire A+B01 before first reads
  stgA(0, 0);
#pragma unroll
  for (int s = 0; s < NJ; ++s) stgB(0, 0, s);
  if constexpr (NJ == 5) WAITV(3); else WAITV(1);
  __builtin_amdgcn_s_barrier();

  for (int t = 0; t < 48; ++t) {
    const int bsel = t & 1, nsel = bsel ^ 1;
    const int kn = (t + 1) * 64;
    const bool st = (t < 47);
    const u16* ldsA = lds + bsel * 16384 + aB0;
    const u16* ldsB = lds + 32768 + bsel * BBUF + bB0;
    bf16x8 af[8], b0, b1, bx[NJ - 2];
    // ---- P0: read af kh0 + bf{0,1} kh0 | stage A(t+1) | vmcnt(4) [B23,B4 of t land]
#pragma unroll
    for (int mi = 0; mi < 8; ++mi) af[mi] = *(const bf16x8*)(ldsA + mi * 1024 + swz0);
    b0 = *(const bf16x8*)(ldsB + swz0);
    b1 = *(const bf16x8*)(ldsB + 4096 + swz0);
    if (st) stgA(kn, nsel);
    asm volatile("" ::: "memory");
    if (st) WAITV(4); else WAITV(0);
    __builtin_amdgcn_s_barrier();
    asm volatile("s_waitcnt lgkmcnt(0)" ::: "memory");
    __builtin_amdgcn_sched_barrier(0);
    __builtin_amdgcn_s_setprio(1);
#pragma unroll
    for (int mi = 0; mi < 8; ++mi) {
      acc[mi][0] = mfma16(af[mi], b0, acc[mi][0]);
      acc[mi][1] = mfma16(af[mi], b1, acc[mi][1]);
    }
    __builtin_amdgcn_s_setprio(0);
    asm volatile("" ::: "memory");
    __builtin_amdgcn_s_barrier();
    // ---- P1: read bf{2..} kh0 | stage B01(t+1)
#pragma unroll
    for (int j = 2; j < NJ; ++j) bx[j - 2] = *(const bf16x8*)(ldsB + j * 4096 + swz0);
    if (st) { stgB(kn, nsel, 0); stgB(kn, nsel, 1); }
    asm volatile("" ::: "memory");
    __builtin_amdgcn_s_barrier();
    asm volatile("s_waitcnt lgkmcnt(0)" ::: "memory");
    __builtin_amdgcn_sched_barrier(0);
    __builtin_amdgcn_s_setprio(1);
#pragma unroll
    for (int mi = 0; mi < 8; ++mi)
#pragma unroll
      for (int j = 2; j < NJ; ++j) acc[mi][j] = mfma16(af[mi], bx[j - 2], acc[mi][j]);
    __builtin_amdgcn_s_setprio(0);
    asm volatile("" ::: "memory");
    __builtin_amdgcn_s_barrier();
    // ---- P2: read af kh1 + bf{0,1} kh1 | stage B23(t+1)
#pragma unroll
    for (int mi = 0; mi < 8; ++mi) af[mi] = *(const bf16x8*)(ldsA + mi * 1024 + swz1);
    b0 = *(const bf16x8*)(ldsB + swz1);
    b1 = *(const bf16x8*)(ldsB + 4096 + swz1);
    if (st) { stgB(kn, nsel, 2); if constexpr (NJ == 5) stgB(kn, nsel, 3); }
    asm volatile("" ::: "memory");
    __builtin_amdgcn_s_barrier();
    asm volatile("s_waitcnt lgkmcnt(0)" ::: "memory");
    __builtin_amdgcn_sched_barrier(0);
    __builtin_amdgcn_s_setprio(1);
#pragma unroll
    for (int mi = 0; mi < 8; ++mi) {
      acc[mi][0] = mfma16(af[mi], b0, acc[mi][0]);
      acc[mi][1] = mfma16(af[mi], b1, acc[mi][1]);
    }
    __builtin_amdgcn_s_setprio(0);
    asm volatile("" ::: "memory");
    __builtin_amdgcn_s_barrier();
    // ---- P3: read bf{2..} kh1 | stage B4(t+1) | vmcnt(NJ-2) [A+B01 of t+1 land]
#pragma unroll
    for (int j = 2; j < NJ; ++j) bx[j - 2] = *(const bf16x8*)(ldsB + j * 4096 + swz1);
    if (st) {
      if constexpr (NJ == 5) stgB(kn, nsel, 4);
      asm volatile("" ::: "memory");
      if constexpr (NJ == 5) WAITV(3); else WAITV(1);
    }
    __builtin_amdgcn_s_barrier();
    asm volatile("s_waitcnt lgkmcnt(0)" ::: "memory");
    __builtin_amdgcn_sched_barrier(0);
    __builtin_amdgcn_s_setprio(1);
#pragma unroll
    for (int mi = 0; mi < 8; ++mi)
#pragma unroll
      for (int j = 2; j < NJ; ++j) acc[mi][j] = mfma16(af[mi], bx[j - 2], acc[mi][j]);
    __builtin_amdgcn_s_setprio(0);
    asm volatile("" ::: "memory");
    __builtin_amdgcn_s_barrier();
  }
  // ---- epilogue (nn = n0 + j*64 + wn*16 + l15)
#pragma unroll
  for (int i = 0; i < 8; ++i)
#pragma unroll
    for (int j = 0; j < NJ; ++j) {
      int nn = n0 + j * 64 + wn * 16 + l15;
      int mmb = m0 + wm * 128 + i * 16 + g * 4;
      if (mode == 1) {
#pragma unroll
        for (int r = 0; r < 4; ++r)
          ((float*)Cv)[(size_t)(mmb + r) * N + nn] = acc[i][j][r];
      } else if (mode == 0) {
#pragma unroll
        for (int r = 0; r < 4; ++r)
          ((u16*)Cv)[(size_t)(mmb + r) * N + nn] = f2b(acc[i][j][r]);
      } else if (mode == 2) {
        u16x4 pk;
#pragma unroll
        for (int r = 0; r < 4; ++r) pk[r] = f2b(acc[i][j][r]);
        *(u16x4*)((u16*)Cv + (size_t)nn * 2048 + (size_t)(mmb >> 11) * 2097152 + (mmb & 2047)) = pk;
      } else {                                 // mode 3: QKV concat routing
        if (nn < 3072) {
#pragma unroll
          for (int r = 0; r < 4; ++r)
            ((u16*)Cv)[(size_t)(mmb + r) * 3072 + nn] = f2b(acc[i][j][r]);
        } else if (nn < 4096) {
#pragma unroll
          for (int r = 0; r < 4; ++r)
            ((u16*)C2)[(size_t)(mmb + r) * 1024 + (nn - 3072)] = f2b(acc[i][j][r]);
        } else {
          int d = nn - 4096;
          u16x4 pk;
#pragma unroll
          for (int r = 0; r < 4; ++r) pk[r] = f2b(acc[i][j][r]);
          *(u16x4*)((u16*)C3 + (size_t)d * 2048 + (size_t)(mmb >> 11) * 2097152 + (mmb & 2047)) = pk;
        }
      }
    }
}

// merged QKV projection: B = concatenated [wq;wk;wv] (5120x3072, contiguous in ws).
// grid 256 = 16 row-panels x 16 col-tiles of 320 -> exactly one full machine round.
__global__ __launch_bounds__(512, 1) void gemm_qkv(const u16* __restrict__ A,
                                                   const u16* __restrict__ Wcat,
                                                   u16* __restrict__ Cq,
                                                   u16* __restrict__ Ck, u16* __restrict__ Cv,
                                                   int K) {
  __shared__ __align__(16) u16 lds[73728];     // 144 KB
  int id = blockIdx.x;
  int s = (id & 7) * 32 + (id >> 3);           // XCD-chunked
  int by = s >> 4, c = s & 15;
  gemm256_body<320>(lds, A, Wcat, Cq, 0, K, by * 256, c * 320, 3, Ck, Cv);
}
// O-projection (f32 out), grid (16,16)
__global__ __launch_bounds__(512, 1) void gemm192_f32(const u16* __restrict__ A, const u16* __restrict__ B,
                                                      float* __restrict__ C, int N, int K) {
  __shared__ __align__(16) u16 lds[57344];
  int bx, by; swz_bid(bx, by);
  gemm256_body<192>(lds, A, B, C, N, K, by * 256, bx * 192, 1);
}

// ---------------- RoPE (in place, bf16) — K only ----------------
__global__ __launch_bounds__(256) void rope_kernel(u16* __restrict__ t, const float* __restrict__ fc,
                                                   const float* __restrict__ fs, int nheads, int total) {
  int idx = blockIdx.x * 256 + threadIdx.x;
  if (idx >= total) return;
  int c = idx & 7;
  int tmp = idx >> 3;
  int h = tmp % nheads;
  int row = tmp / nheads;
  int s = row & (S_LEN - 1);
  int d0 = c << 3;
  u16* base = t + (size_t)row * (nheads * 128) + h * 128;
  u16x8 lo = *(const u16x8*)(base + d0);
  u16x8 hi = *(const u16x8*)(base + 64 + d0);
  const float* cp = fc + s * 64 + d0;
  const float* sp = fs + s * 64 + d0;
  u16x8 olo, ohi;
#pragma unroll
  for (int j = 0; j < 8; ++j) {
    float cv = cp[j], sn = sp[j];
    float a = b2f(lo[j]), b = b2f(hi[j]);
    olo[j] = f2b(a * cv - b * sn);
    ohi[j] = f2b(b * cv + a * sn);
  }
  *(u16x8*)(base + d0) = olo;
  *(u16x8*)(base + 64 + d0) = ohi;
}

// ---------------- causal GQA flash attention — single-panel LPT blocks (r12) ----------------
__global__ __launch_bounds__(256, 2) void attn_kernel(const u16* __restrict__ xq,
                                                      const u16* __restrict__ xk,
                                                      const u16* __restrict__ xvT,
                                                      const float* __restrict__ fc,
                                                      const float* __restrict__ fs,
                                                      u16* __restrict__ o,
                                                      const float* __restrict__ wo,
                                                      u16* __restrict__ wob) {
  __shared__ __align__(16) u16 smem[40960];    // 80 KB: K dbuf 32K + V dbuf 32K + P 16K
  if (blockIdx.x >= 768) {                     // cvt(wo) backfill blocks
    int i = (blockIdx.x - 768) * 256 + threadIdx.x;   // 4608*256 = 1179648 exactly
    cvt_one(wo, wob, i);
    return;
  }
  const int tid = threadIdx.x;
  const int w = tid >> 6, lane = tid & 63;
  const int l15 = lane & 15, g = lane >> 4;
  const int id = blockIdx.x;
  const int xcd = id & 7, slot = id >> 3;      // slot in [0,96)
  const int grp = xcd + 8 * (slot / 48);       // (b,kvh) group, 0..15
  const int s48 = slot % 48;
  const int b = grp >> 3, kvh = grp & 7;
  const int qb = 15 - s48 / 3;                 // qb descending (LPT)
  const int h = kvh * 3 + s48 % 3;
  const float sc2 = 0.08838834764831845f * 1.4426950408889634f;  // 1/sqrt(128)*log2e

  const u16* ksrc = xk + (size_t)b * 2097152 + kvh * 128;          // [s][1024]
  const u16* vsrc = xvT + (size_t)(b * 1024 + kvh * 128) * 2048;   // [d][2048]
  int koff[4], vofs[4], dst4[4];
#pragma unroll
  for (int r = 0; r < 4; ++r) {
    int c = r * 256 + tid;
    int krow = c >> 4, kj = (c & 15) ^ (krow & 7);   // K: 64 rows x 16 chunks
    koff[r] = krow * 1024 + kj * 8;
    int vrow = c >> 3, vj = (c & 7) ^ (vrow & 7);    // V^T: 128 rows x 8 chunks
    vofs[r] = vrow * 2048 + vj * 8;
    dst4[r] = (r * 256 + (tid & 192)) * 8;           // wave-uniform LDS chunk base
  }
  u16* sPw = smem + 32768 + w * 2048;          // per-wave P: 2 sets x 1024 u16
  const int pxr = (l15 & 7) << 3;

  const int q0 = qb * 128;

  // Q load + fused RoPE + pre-scale, 2 sets
  bf16x8 qf[2][4];
#pragma unroll
  for (int s = 0; s < 2; ++s) {
    const int qrow = q0 + w * 32 + s * 16 + l15;
    const u16* qptr = xq + (size_t)(b * S_LEN + qrow) * DM + h * 128;
#pragma unroll
    for (int dcp = 0; dcp < 2; ++dcp) {
      u16x8 Lo = *(const u16x8*)(qptr + dcp * 32 + g * 8);
      u16x8 Hi = *(const u16x8*)(qptr + 64 + dcp * 32 + g * 8);
      const float* cp = fc + qrow * 64 + dcp * 32 + g * 8;
      const float* sp = fs + qrow * 64 + dcp * 32 + g * 8;
      bf16x8 qlo, qhi;
#pragma unroll
      for (int j = 0; j < 8; ++j) {
        float cv = cp[j], sn = sp[j];
        float a = b2f(Lo[j]), bb = b2f(Hi[j]);
        qlo[j] = (__bf16)((a * cv - bb * sn) * sc2);
        qhi[j] = (__bf16)((bb * cv + a * sn) * sc2);
      }
      qf[s][dcp] = qlo;
      qf[s][dcp + 2] = qhi;
    }
  }

  u16 *sKc = smem, *sKn = smem + 8192;
  u16 *sVc = smem + 16384, *sVn = smem + 24576;

  f32x4 accO[2][8];
#pragma unroll
  for (int s = 0; s < 2; ++s)
#pragma unroll
    for (int i = 0; i < 8; ++i) accO[s][i] = 0.f;
  float m_[2] = {-1e30f, -1e30f}, ls_[2] = {0.f, 0.f};
  const int nt = 2 * qb + 2;

#pragma unroll
  for (int r = 0; r < 4; ++r) gload16(ksrc + koff[r], sKc + dst4[r]);
#pragma unroll
  for (int r = 0; r < 4; ++r) gload16(vsrc + vofs[r], sVc + dst4[r]);
  __syncthreads();

  for (int t = 0; t < nt; ++t) {
    if (t + 1 < nt) {
      int k0n = (t + 1) * 64;
#pragma unroll
      for (int r = 0; r < 4; ++r) gload16(ksrc + (size_t)k0n * 1024 + koff[r], sKn + dst4[r]);
#pragma unroll
      for (int r = 0; r < 4; ++r) gload16(vsrc + k0n + vofs[r], sVn + dst4[r]);
    }
    if (64 * t <= q0 + w * 32 + 31) {           // wave-level causal skip
      f32x4 st[2][4];
      __builtin_amdgcn_s_setprio(1);
#pragma unroll
      for (int kt = 0; kt < 4; ++kt) {
        int row = kt * 16 + l15;
        bf16x8 kf[4];
#pragma unroll
        for (int dc = 0; dc < 4; ++dc)
          kf[dc] = *(const bf16x8*)(sKc + row * 128 + ((dc * 32 + g * 8) ^ ((row & 7) << 3)));
        f32x4 a0 = 0.f, a1 = 0.f;
#pragma unroll
        for (int dc = 0; dc < 4; ++dc) {
          a0 = mfma16(kf[dc], qf[0][dc], a0);
          a1 = mfma16(kf[dc], qf[1][dc], a1);
        }
        st[0][kt] = a0;
        st[1][kt] = a1;
      }
      __builtin_amdgcn_s_setprio(0);
#pragma unroll
      for (int s = 0; s < 2; ++s) {
        const int qrow = q0 + w * 32 + s * 16 + l15;
        float pmax = -1e30f;
#pragma unroll
        for (int kt = 0; kt < 4; ++kt)
#pragma unroll
          for (int r = 0; r < 4; ++r) {
            float x = st[s][kt][r];
            if (t >= nt - 2) {
              int kk = t * 64 + kt * 16 + g * 4 + r;
              if (kk > qrow) x = -1e30f;
            }
            st[s][kt][r] = x;
            pmax = fmaxf(pmax, x);
          }
        pmax = fmaxf(pmax, __shfl_xor(pmax, 16));
        pmax = fmaxf(pmax, __shfl_xor(pmax, 32));
        if (!__all(pmax - m_[s] <= 8.0f)) {    // defer-max
          float mnew = fmaxf(m_[s], pmax);
          float corr = exp2f(m_[s] - mnew);
          ls_[s] *= corr;
#pragma unroll
          for (int i = 0; i < 8; ++i) accO[s][i] *= corr;
          m_[s] = mnew;
        }
        float ps = 0.f;
#pragma unroll
        for (int kt = 0; kt < 4; ++kt) {
          u16x4 pk;
#pragma unroll
          for (int r = 0; r < 4; ++r) {
            float p = exp2f(st[s][kt][r] - m_[s]);
            ps += p;
            pk[r] = f2b(p);
          }
          *(u16x4*)(sPw + s * 1024 + ((l15 * 64 + kt * 16 + g * 4) ^ pxr)) = pk;
        }
        ps += __shfl_xor(ps, 16);
        ps += __shfl_xor(ps, 32);
        ls_[s] += ps;
      }
      bf16x8 pf[2][2];
#pragma unroll
      for (int s = 0; s < 2; ++s)
#pragma unroll
        for (int ck = 0; ck < 2; ++ck)
          pf[s][ck] = *(const bf16x8*)(sPw + s * 1024 + ((l15 * 64 + ck * 32 + g * 8) ^ pxr));
      __builtin_amdgcn_s_setprio(1);
#pragma unroll
      for (int dt = 0; dt < 8; ++dt) {
        int row = dt * 16 + l15;
#pragma unroll
        for (int ck = 0; ck < 2; ++ck) {
          bf16x8 vf = *(const bf16x8*)(sVc + row * 64 + ((ck * 32 + g * 8) ^ ((row & 7) << 3)));
          accO[0][dt] = mfma16(vf, pf[0][ck], accO[0][dt]);
          accO[1][dt] = mfma16(vf, pf[1][ck], accO[1][dt]);
        }
      }
      __builtin_amdgcn_s_setprio(0);
    }
    __syncthreads();                            // drains stage vmcnt + cur reads done
    u16* tk = sKc; sKc = sKn; sKn = tk;
    u16* tv = sVc; sVc = sVn; sVn = tv;
  }
  // epilogue: per-wave [32 q][128 d] transpose in (dead) K/V LDS region
  u16* sOw = smem + w * 8192;
#pragma unroll
  for (int s = 0; s < 2; ++s) {
    float invl = 1.0f / ls_[s];
#pragma unroll
    for (int dt = 0; dt < 8; ++dt)
#pragma unroll
      for (int r = 0; r < 4; ++r) {
        int d = dt * 16 + g * 4 + r;
        sOw[((s * 16 + l15) * 128 + d) ^ pxr] = f2b(accO[s][dt][r] * invl);
      }
  }
#pragma unroll
  for (int p = 0; p < 8; ++p) {
    int idx = p * 64 + lane;
    int q = idx >> 4, c = idx & 15;
    int j = c ^ (q & 7);
    u32x4 v = *(const u32x4*)(sOw + q * 128 + j * 8);
    *(u32x4*)(o + (size_t)(b * S_LEN + q0 + w * 32 + q) * DM + h * 128 + c * 8) = v;
  }
}

// ---------------- launch ----------------
extern "C" void kernel_launch(void* const* d_in, const int* in_sizes, int n_in,
                              void* d_out, int out_size, void* d_ws, size_t ws_size,
                              hipStream_t stream) {
  const float* x  = (const float*)d_in[0];
  const float* fc = (const float*)d_in[1];
  const float* fs = (const float*)d_in[2];
  const float* wq = (const float*)d_in[4];
  const float* wk = (const float*)d_in[5];
  const float* wv = (const float*)d_in[6];
  const float* wo = (const float*)d_in[7];
  float* out = (float*)d_out;
  char* ws = (char*)d_ws;

  u16* xb  = (u16*)(ws);                 // x bf16      25,165,824
  u16* wqb = (u16*)(ws + 25165824);      // wq bf16     18,874,368 ┐ contiguous = Wcat
  u16* att = (u16*)(ws + 25165824);      // attn out (aliases wq/wk after death)
  u16* wkb = (u16*)(ws + 44040192);      // wk bf16      6,291,456 │ (5120 x 3072)
  u16* wvb = (u16*)(ws + 50331648);      // wv bf16      6,291,456 ┘
  u16* xqb = (u16*)(ws + 56623104);      // xq bf16     25,165,824
  u16* xkb = (u16*)(ws + 81788928);      // xk bf16      8,388,608
  u16* xvT = (u16*)(ws + 90177536);      // V^T bf16     8,388,608
  u16* wob = (u16*)(ws);                 // wo bf16 (aliases xb, dead after gemm_qkv)

  cvt4_kernel<<<13824, 256, 0, stream>>>(x, xb, wq, wqb, wk, wkb, wv, wvb);

  gemm_qkv<<<256, 512, 0, stream>>>(xb, wqb, xqb, xkb, xvT, 3072);

  rope_kernel<<<1024, 256, 0, stream>>>(xkb, fc, fs, NKV, 4096 * NKV * 8);  // K only

  attn_kernel<<<5376, 256, 0, stream>>>(xqb, xkb, xvT, fc, fs, att, wo, wob);

  gemm192_f32<<<dim3(16, 16), 512, 0, stream>>>(att, wob, out, 3072, 3072);
}

// Round 15
// 307.766 us; speedup vs baseline: 2.4820x; 1.0187x over previous
//
#include <hip/hip_runtime.h>

typedef unsigned short u16;
typedef unsigned int u32;
typedef __attribute__((ext_vector_type(8))) __bf16 bf16x8;
typedef __attribute__((ext_vector_type(4))) float f32x4;
typedef __attribute__((ext_vector_type(4))) u32 u32x4;
typedef __attribute__((ext_vector_type(2))) u32 u32x2;
typedef __attribute__((ext_vector_type(8))) u16 u16x8;
typedef __attribute__((ext_vector_type(4))) u16 u16x4;

#define S_LEN 2048
#define DM 3072
#define NH 24
#define NKV 8

#define WAITV(n) asm volatile("s_waitcnt vmcnt(" #n ")" ::: "memory")

__device__ __forceinline__ u16 f2b(float f) {
  u32 u = __builtin_bit_cast(u32, f);
  u = u + 0x7FFFu + ((u >> 16) & 1u);
  return (u16)(u >> 16);
}
__device__ __forceinline__ float b2f(u16 h) {
  u32 u = ((u32)h) << 16;
  return __builtin_bit_cast(float, u);
}
__device__ __forceinline__ u32 cvtpk(float lo, float hi) {
  u32 r;
  asm("v_cvt_pk_bf16_f32 %0, %1, %2" : "=v"(r) : "v"(lo), "v"(hi));
  return r;
}
__device__ __forceinline__ f32x4 mfma16(bf16x8 a, bf16x8 b, f32x4 c) {
  return __builtin_amdgcn_mfma_f32_16x16x32_bf16(a, b, c, 0, 0, 0);
}
__device__ __forceinline__ void gload16(const u16* g, u16* l) {
  __builtin_amdgcn_global_load_lds((const __attribute__((address_space(1))) void*)g,
                                   (__attribute__((address_space(3))) void*)l, 16, 0, 0);
}

// ---------------- f32 -> bf16 conversion ----------------
__device__ __forceinline__ void cvt_one(const float* __restrict__ s, u16* __restrict__ d, int j) {
  const f32x4* p = (const f32x4*)(s + (size_t)j * 8);
  f32x4 a = p[0], b = p[1];
  u16x8 o;
#pragma unroll
  for (int q = 0; q < 4; ++q) { o[q] = f2b(a[q]); o[q + 4] = f2b(b[q]); }
  *(u16x8*)(d + (size_t)j * 8) = o;
}
__global__ __launch_bounds__(256) void cvt4_kernel(const float* __restrict__ s0, u16* __restrict__ d0,
                                                   const float* __restrict__ s1, u16* __restrict__ d1,
                                                   const float* __restrict__ s2, u16* __restrict__ d2,
                                                   const float* __restrict__ s3, u16* __restrict__ d3) {
  int i = blockIdx.x * 256 + threadIdx.x;
  if (i < 1572864)      cvt_one(s0, d0, i);
  else if (i < 2752512) cvt_one(s1, d1, i - 1572864);
  else if (i < 3145728) cvt_one(s2, d2, i - 2752512);
  else                  cvt_one(s3, d3, i - 3145728);
}

// ---------------- XCD-aware block swizzle ----------------
__device__ __forceinline__ void swz_bid(int& bx, int& by) {
  int gx = gridDim.x;
  int tot = gx * gridDim.y;          // must be divisible by 8
  int id = blockIdx.y * gx + blockIdx.x;
  int cpx = tot >> 3;
  int s = (id & 7) * cpx + (id >> 3);
  bx = s % gx;
  by = s / gx;
}

// ---------------- counted-vmcnt phase-interleaved GEMM (T4, r14-proven) ----------------
template <int BN>
__device__ __forceinline__ void gemm256_body(u16* __restrict__ lds,
                                             const u16* __restrict__ A, const u16* __restrict__ B,
                                             void* __restrict__ Cv, int N, int K,
                                             int m0, int n0, int mode,
                                             void* __restrict__ C2 = nullptr,
                                             void* __restrict__ C3 = nullptr) {
  constexpr int NJ = BN / 64;                  // B slots / per-wave n-frags (5 or 3)
  constexpr int BBUF = NJ * 4096;              // B u16 per buffer
  const int tid = threadIdx.x;
  const int lane = tid & 63;
  const int w = tid >> 6;
  const int l15 = lane & 15, g = lane >> 4;
  const int wm = w >> 2, wn = w & 3;
  const int srow = tid >> 3;
  const int scol = ((tid & 7) ^ (srow & 7)) * 8;
  const u16* aS = A + (size_t)(m0 + srow) * K + scol;
  const u16* bS = B + (size_t)(n0 + srow) * K + scol;
  const int sdst = (tid & 448) * 8;
  const int swz0 = (g ^ (l15 & 7)) * 8;
  const int swz1 = ((4 + g) ^ (l15 & 7)) * 8;
  const int aB0 = wm * 8192 + l15 * 64;
  const int bB0 = wn * 1024 + l15 * 64;        // within-slot row = wn*16 + l15

  f32x4 acc[8][NJ];
#pragma unroll
  for (int i = 0; i < 8; ++i)
#pragma unroll
    for (int j = 0; j < NJ; ++j) acc[i][j] = 0.f;

  auto stgA = [&](int k0, int bsel) {
#pragma unroll
    for (int s = 0; s < 4; ++s)
      gload16(aS + (size_t)(s * 64) * K + k0, lds + bsel * 16384 + s * 4096 + sdst);
  };
  auto stgB = [&](int k0, int bsel, int s) {
    gload16(bS + (size_t)(s * 64) * K + k0, lds + 32768 + bsel * BBUF + s * 4096 + sdst);
  };

  // prologue: tile 0 (A, then B slots ascending), retire A+B01 before first reads
  stgA(0, 0);
#pragma unroll
  for (int s = 0; s < NJ; ++s) stgB(0, 0, s);
  if constexpr (NJ == 5) WAITV(3); else WAITV(1);
  __builtin_amdgcn_s_barrier();

  for (int t = 0; t < 48; ++t) {
    const int bsel = t & 1, nsel = bsel ^ 1;
    const int kn = (t + 1) * 64;
    const bool st = (t < 47);
    const u16* ldsA = lds + bsel * 16384 + aB0;
    const u16* ldsB = lds + 32768 + bsel * BBUF + bB0;
    bf16x8 af[8], b0, b1, bx[NJ - 2];
    // ---- P0: read af kh0 + bf{0,1} kh0 | stage A(t+1) | vmcnt(4) [B23,B4 of t land]
#pragma unroll
    for (int mi = 0; mi < 8; ++mi) af[mi] = *(const bf16x8*)(ldsA + mi * 1024 + swz0);
    b0 = *(const bf16x8*)(ldsB + swz0);
    b1 = *(const bf16x8*)(ldsB + 4096 + swz0);
    if (st) stgA(kn, nsel);
    asm volatile("" ::: "memory");
    if (st) WAITV(4); else WAITV(0);
    __builtin_amdgcn_s_barrier();
    asm volatile("s_waitcnt lgkmcnt(0)" ::: "memory");
    __builtin_amdgcn_sched_barrier(0);
    __builtin_amdgcn_s_setprio(1);
#pragma unroll
    for (int mi = 0; mi < 8; ++mi) {
      acc[mi][0] = mfma16(af[mi], b0, acc[mi][0]);
      acc[mi][1] = mfma16(af[mi], b1, acc[mi][1]);
    }
    __builtin_amdgcn_s_setprio(0);
    asm volatile("" ::: "memory");
    __builtin_amdgcn_s_barrier();
    // ---- P1: read bf{2..} kh0 | stage B01(t+1)
#pragma unroll
    for (int j = 2; j < NJ; ++j) bx[j - 2] = *(const bf16x8*)(ldsB + j * 4096 + swz0);
    if (st) { stgB(kn, nsel, 0); stgB(kn, nsel, 1); }
    asm volatile("" ::: "memory");
    __builtin_amdgcn_s_barrier();
    asm volatile("s_waitcnt lgkmcnt(0)" ::: "memory");
    __builtin_amdgcn_sched_barrier(0);
    __builtin_amdgcn_s_setprio(1);
#pragma unroll
    for (int mi = 0; mi < 8; ++mi)
#pragma unroll
      for (int j = 2; j < NJ; ++j) acc[mi][j] = mfma16(af[mi], bx[j - 2], acc[mi][j]);
    __builtin_amdgcn_s_setprio(0);
    asm volatile("" ::: "memory");
    __builtin_amdgcn_s_barrier();
    // ---- P2: read af kh1 + bf{0,1} kh1 | stage B23(t+1)
#pragma unroll
    for (int mi = 0; mi < 8; ++mi) af[mi] = *(const bf16x8*)(ldsA + mi * 1024 + swz1);
    b0 = *(const bf16x8*)(ldsB + swz1);
    b1 = *(const bf16x8*)(ldsB + 4096 + swz1);
    if (st) { stgB(kn, nsel, 2); if constexpr (NJ == 5) stgB(kn, nsel, 3); }
    asm volatile("" ::: "memory");
    __builtin_amdgcn_s_barrier();
    asm volatile("s_waitcnt lgkmcnt(0)" ::: "memory");
    __builtin_amdgcn_sched_barrier(0);
    __builtin_amdgcn_s_setprio(1);
#pragma unroll
    for (int mi = 0; mi < 8; ++mi) {
      acc[mi][0] = mfma16(af[mi], b0, acc[mi][0]);
      acc[mi][1] = mfma16(af[mi], b1, acc[mi][1]);
    }
    __builtin_amdgcn_s_setprio(0);
    asm volatile("" ::: "memory");
    __builtin_amdgcn_s_barrier();
    // ---- P3: read bf{2..} kh1 | stage B4(t+1) | vmcnt(NJ-2) [A+B01 of t+1 land]
#pragma unroll
    for (int j = 2; j < NJ; ++j) bx[j - 2] = *(const bf16x8*)(ldsB + j * 4096 + swz1);
    if (st) {
      if constexpr (NJ == 5) stgB(kn, nsel, 4);
      asm volatile("" ::: "memory");
      if constexpr (NJ == 5) WAITV(3); else WAITV(1);
    }
    __builtin_amdgcn_s_barrier();
    asm volatile("s_waitcnt lgkmcnt(0)" ::: "memory");
    __builtin_amdgcn_sched_barrier(0);
    __builtin_amdgcn_s_setprio(1);
#pragma unroll
    for (int mi = 0; mi < 8; ++mi)
#pragma unroll
      for (int j = 2; j < NJ; ++j) acc[mi][j] = mfma16(af[mi], bx[j - 2], acc[mi][j]);
    __builtin_amdgcn_s_setprio(0);
    asm volatile("" ::: "memory");
    __builtin_amdgcn_s_barrier();
  }
  // ---- epilogue (nn = n0 + j*64 + wn*16 + l15)
#pragma unroll
  for (int i = 0; i < 8; ++i)
#pragma unroll
    for (int j = 0; j < NJ; ++j) {
      int nn = n0 + j * 64 + wn * 16 + l15;
      int mmb = m0 + wm * 128 + i * 16 + g * 4;
      if (mode == 1) {
#pragma unroll
        for (int r = 0; r < 4; ++r)
          ((float*)Cv)[(size_t)(mmb + r) * N + nn] = acc[i][j][r];
      } else if (mode == 0) {
#pragma unroll
        for (int r = 0; r < 4; ++r)
          ((u16*)Cv)[(size_t)(mmb + r) * N + nn] = f2b(acc[i][j][r]);
      } else if (mode == 2) {
        u16x4 pk;
#pragma unroll
        for (int r = 0; r < 4; ++r) pk[r] = f2b(acc[i][j][r]);
        *(u16x4*)((u16*)Cv + (size_t)nn * 2048 + (size_t)(mmb >> 11) * 2097152 + (mmb & 2047)) = pk;
      } else {                                 // mode 3: QKV concat routing
        if (nn < 3072) {
#pragma unroll
          for (int r = 0; r < 4; ++r)
            ((u16*)Cv)[(size_t)(mmb + r) * 3072 + nn] = f2b(acc[i][j][r]);
        } else if (nn < 4096) {
#pragma unroll
          for (int r = 0; r < 4; ++r)
            ((u16*)C2)[(size_t)(mmb + r) * 1024 + (nn - 3072)] = f2b(acc[i][j][r]);
        } else {
          int d = nn - 4096;
          u16x4 pk;
#pragma unroll
          for (int r = 0; r < 4; ++r) pk[r] = f2b(acc[i][j][r]);
          *(u16x4*)((u16*)C3 + (size_t)d * 2048 + (size_t)(mmb >> 11) * 2097152 + (mmb & 2047)) = pk;
        }
      }
    }
}

// merged QKV projection: B = concatenated [wq;wk;wv] (5120x3072, contiguous in ws).
__global__ __launch_bounds__(512, 1) void gemm_qkv(const u16* __restrict__ A,
                                                   const u16* __restrict__ Wcat,
                                                   u16* __restrict__ Cq,
                                                   u16* __restrict__ Ck, u16* __restrict__ Cv,
                                                   int K) {
  __shared__ __align__(16) u16 lds[73728];     // 144 KB
  int id = blockIdx.x;
  int s = (id & 7) * 32 + (id >> 3);           // XCD-chunked
  int by = s >> 4, c = s & 15;
  gemm256_body<320>(lds, A, Wcat, Cq, 0, K, by * 256, c * 320, 3, Ck, Cv);
}
// O-projection (f32 out), grid (16,16)
__global__ __launch_bounds__(512, 1) void gemm192_f32(const u16* __restrict__ A, const u16* __restrict__ B,
                                                      float* __restrict__ C, int N, int K) {
  __shared__ __align__(16) u16 lds[57344];
  int bx, by; swz_bid(bx, by);
  gemm256_body<192>(lds, A, B, C, N, K, by * 256, bx * 192, 1);
}

// ---------------- RoPE (in place, bf16) — K only ----------------
__global__ __launch_bounds__(256) void rope_kernel(u16* __restrict__ t, const float* __restrict__ fc,
                                                   const float* __restrict__ fs, int nheads, int total) {
  int idx = blockIdx.x * 256 + threadIdx.x;
  if (idx >= total) return;
  int c = idx & 7;
  int tmp = idx >> 3;
  int h = tmp % nheads;
  int row = tmp / nheads;
  int s = row & (S_LEN - 1);
  int d0 = c << 3;
  u16* base = t + (size_t)row * (nheads * 128) + h * 128;
  u16x8 lo = *(const u16x8*)(base + d0);
  u16x8 hi = *(const u16x8*)(base + 64 + d0);
  const float* cp = fc + s * 64 + d0;
  const float* sp = fs + s * 64 + d0;
  u16x8 olo, ohi;
#pragma unroll
  for (int j = 0; j < 8; ++j) {
    float cv = cp[j], sn = sp[j];
    float a = b2f(lo[j]), b = b2f(hi[j]);
    olo[j] = f2b(a * cv - b * sn);
    ohi[j] = f2b(b * cv + a * sn);
  }
  *(u16x8*)(base + d0) = olo;
  *(u16x8*)(base + 64 + d0) = ohi;
}

// ---------------- causal GQA flash attention — single-panel LPT blocks ----------------
// r14 structure + VALU cuts: cvtpk P-packing (u32x2 stores), per-lane partial
// lsum (cross-lane reduce once per panel, not per tile), tree-max, cvtpk epilogue.
__global__ __launch_bounds__(256, 2) void attn_kernel(const u16* __restrict__ xq,
                                                      const u16* __restrict__ xk,
                                                      const u16* __restrict__ xvT,
                                                      const float* __restrict__ fc,
                                                      const float* __restrict__ fs,
                                                      u16* __restrict__ o,
                                                      const float* __restrict__ wo,
                                                      u16* __restrict__ wob) {
  __shared__ __align__(16) u16 smem[40960];    // 80 KB: K dbuf 32K + V dbuf 32K + P 16K
  if (blockIdx.x >= 768) {                     // cvt(wo) backfill blocks
    int i = (blockIdx.x - 768) * 256 + threadIdx.x;   // 4608*256 = 1179648 exactly
    cvt_one(wo, wob, i);
    return;
  }
  const int tid = threadIdx.x;
  const int w = tid >> 6, lane = tid & 63;
  const int l15 = lane & 15, g = lane >> 4;
  const int id = blockIdx.x;
  const int xcd = id & 7, slot = id >> 3;      // slot in [0,96)
  const int grp = xcd + 8 * (slot / 48);       // (b,kvh) group, 0..15
  const int s48 = slot % 48;
  const int b = grp >> 3, kvh = grp & 7;
  const int qb = 15 - s48 / 3;                 // qb descending (LPT)
  const int h = kvh * 3 + s48 % 3;
  const float sc2 = 0.08838834764831845f * 1.4426950408889634f;  // 1/sqrt(128)*log2e

  const u16* ksrc = xk + (size_t)b * 2097152 + kvh * 128;          // [s][1024]
  const u16* vsrc = xvT + (size_t)(b * 1024 + kvh * 128) * 2048;   // [d][2048]
  int koff[4], vofs[4], dst4[4];
#pragma unroll
  for (int r = 0; r < 4; ++r) {
    int c = r * 256 + tid;
    int krow = c >> 4, kj = (c & 15) ^ (krow & 7);   // K: 64 rows x 16 chunks
    koff[r] = krow * 1024 + kj * 8;
    int vrow = c >> 3, vj = (c & 7) ^ (vrow & 7);    // V^T: 128 rows x 8 chunks
    vofs[r] = vrow * 2048 + vj * 8;
    dst4[r] = (r * 256 + (tid & 192)) * 8;           // wave-uniform LDS chunk base
  }
  u16* sPw = smem + 32768 + w * 2048;          // per-wave P: 2 sets x 1024 u16
  const int pxr = (l15 & 7) << 3;

  const int q0 = qb * 128;

  // Q load + fused RoPE + pre-scale, 2 sets
  bf16x8 qf[2][4];
#pragma unroll
  for (int s = 0; s < 2; ++s) {
    const int qrow = q0 + w * 32 + s * 16 + l15;
    const u16* qptr = xq + (size_t)(b * S_LEN + qrow) * DM + h * 128;
#pragma unroll
    for (int dcp = 0; dcp < 2; ++dcp) {
      u16x8 Lo = *(const u16x8*)(qptr + dcp * 32 + g * 8);
      u16x8 Hi = *(const u16x8*)(qptr + 64 + dcp * 32 + g * 8);
      const float* cp = fc + qrow * 64 + dcp * 32 + g * 8;
      const float* sp = fs + qrow * 64 + dcp * 32 + g * 8;
      bf16x8 qlo, qhi;
#pragma unroll
      for (int j = 0; j < 8; ++j) {
        float cv = cp[j], sn = sp[j];
        float a = b2f(Lo[j]), bb = b2f(Hi[j]);
        qlo[j] = (__bf16)((a * cv - bb * sn) * sc2);
        qhi[j] = (__bf16)((bb * cv + a * sn) * sc2);
      }
      qf[s][dcp] = qlo;
      qf[s][dcp + 2] = qhi;
    }
  }

  u16 *sKc = smem, *sKn = smem + 8192;
  u16 *sVc = smem + 16384, *sVn = smem + 24576;

  f32x4 accO[2][8];
#pragma unroll
  for (int s = 0; s < 2; ++s)
#pragma unroll
    for (int i = 0; i < 8; ++i) accO[s][i] = 0.f;
  float m_[2] = {-1e30f, -1e30f}, ls_[2] = {0.f, 0.f};
  const int nt = 2 * qb + 2;

#pragma unroll
  for (int r = 0; r < 4; ++r) gload16(ksrc + koff[r], sKc + dst4[r]);
#pragma unroll
  for (int r = 0; r < 4; ++r) gload16(vsrc + vofs[r], sVc + dst4[r]);
  __syncthreads();

  for (int t = 0; t < nt; ++t) {
    if (t + 1 < nt) {
      int k0n = (t + 1) * 64;
#pragma unroll
      for (int r = 0; r < 4; ++r) gload16(ksrc + (size_t)k0n * 1024 + koff[r], sKn + dst4[r]);
#pragma unroll
      for (int r = 0; r < 4; ++r) gload16(vsrc + k0n + vofs[r], sVn + dst4[r]);
    }
    if (64 * t <= q0 + w * 32 + 31) {           // wave-level causal skip
      f32x4 st[2][4];
      __builtin_amdgcn_s_setprio(1);
#pragma unroll
      for (int kt = 0; kt < 4; ++kt) {
        int row = kt * 16 + l15;
        bf16x8 kf[4];
#pragma unroll
        for (int dc = 0; dc < 4; ++dc)
          kf[dc] = *(const bf16x8*)(sKc + row * 128 + ((dc * 32 + g * 8) ^ ((row & 7) << 3)));
        f32x4 a0 = 0.f, a1 = 0.f;
#pragma unroll
        for (int dc = 0; dc < 4; ++dc) {
          a0 = mfma16(kf[dc], qf[0][dc], a0);
          a1 = mfma16(kf[dc], qf[1][dc], a1);
        }
        st[0][kt] = a0;
        st[1][kt] = a1;
      }
      __builtin_amdgcn_s_setprio(0);
      // softmax per set: mask, tree-max, defer-max, exp2, cvtpk pack, partial lsum
#pragma unroll
      for (int s = 0; s < 2; ++s) {
        const int qrow = q0 + w * 32 + s * 16 + l15;
#pragma unroll
        for (int kt = 0; kt < 4; ++kt)
#pragma unroll
          for (int r = 0; r < 4; ++r) {
            float x = st[s][kt][r];
            if (t >= nt - 2) {
              int kk = t * 64 + kt * 16 + g * 4 + r;
              if (kk > qrow) x = -1e30f;
            }
            st[s][kt][r] = x;
          }
        float pm0 = fmaxf(fmaxf(st[s][0][0], st[s][0][1]), fmaxf(st[s][0][2], st[s][0][3]));
        float pm1 = fmaxf(fmaxf(st[s][1][0], st[s][1][1]), fmaxf(st[s][1][2], st[s][1][3]));
        float pm2 = fmaxf(fmaxf(st[s][2][0], st[s][2][1]), fmaxf(st[s][2][2], st[s][2][3]));
        float pm3 = fmaxf(fmaxf(st[s][3][0], st[s][3][1]), fmaxf(st[s][3][2], st[s][3][3]));
        float pmax = fmaxf(fmaxf(pm0, pm1), fmaxf(pm2, pm3));
        pmax = fmaxf(pmax, __shfl_xor(pmax, 16));
        pmax = fmaxf(pmax, __shfl_xor(pmax, 32));
        if (!__all(pmax - m_[s] <= 8.0f)) {    // defer-max
          float mnew = fmaxf(m_[s], pmax);
          float corr = exp2f(m_[s] - mnew);
          ls_[s] *= corr;
#pragma unroll
          for (int i = 0; i < 8; ++i) accO[s][i] *= corr;
          m_[s] = mnew;
        }
        float ps = 0.f;
#pragma unroll
        for (int kt = 0; kt < 4; ++kt) {
          float p0 = exp2f(st[s][kt][0] - m_[s]);
          float p1 = exp2f(st[s][kt][1] - m_[s]);
          float p2 = exp2f(st[s][kt][2] - m_[s]);
          float p3 = exp2f(st[s][kt][3] - m_[s]);
          ps += (p0 + p1) + (p2 + p3);
          u32x2 pr;
          pr[0] = cvtpk(p0, p1);
          pr[1] = cvtpk(p2, p3);
          *(u32x2*)(sPw + s * 1024 + ((l15 * 64 + kt * 16 + g * 4) ^ pxr)) = pr;
        }
        ls_[s] += ps;                          // per-lane partial; reduce at epilogue
      }
      // P fragments (wave-local LDS)
      bf16x8 pf[2][2];
#pragma unroll
      for (int s = 0; s < 2; ++s)
#pragma unroll
        for (int ck = 0; ck < 2; ++ck)
          pf[s][ck] = *(const bf16x8*)(sPw + s * 1024 + ((l15 * 64 + ck * 32 + g * 8) ^ pxr));
      // PV both sets: each vf read feeds 2 MFMAs
      __builtin_amdgcn_s_setprio(1);
#pragma unroll
      for (int dt = 0; dt < 8; ++dt) {
        int row = dt * 16 + l15;
#pragma unroll
        for (int ck = 0; ck < 2; ++ck) {
          bf16x8 vf = *(const bf16x8*)(sVc + row * 64 + ((ck * 32 + g * 8) ^ ((row & 7) << 3)));
          accO[0][dt] = mfma16(vf, pf[0][ck], accO[0][dt]);
          accO[1][dt] = mfma16(vf, pf[1][ck], accO[1][dt]);
        }
      }
      __builtin_amdgcn_s_setprio(0);
    }
    __syncthreads();                            // drains stage vmcnt + cur reads done
    u16* tk = sKc; sKc = sKn; sKn = tk;
    u16* tv = sVc; sVc = sVn; sVn = tv;
  }
  // cross-lane lsum reduce (deferred from the k-loop)
#pragma unroll
  for (int s = 0; s < 2; ++s) {
    ls_[s] += __shfl_xor(ls_[s], 16);
    ls_[s] += __shfl_xor(ls_[s], 32);
  }
  // epilogue: per-wave [32 q][128 d] transpose in (dead) K/V LDS region
  u16* sOw = smem + w * 8192;
#pragma unroll
  for (int s = 0; s < 2; ++s) {
    float invl = 1.0f / ls_[s];
#pragma unroll
    for (int dt = 0; dt < 8; ++dt) {
      u32x2 pr;
      pr[0] = cvtpk(accO[s][dt][0] * invl, accO[s][dt][1] * invl);
      pr[1] = cvtpk(accO[s][dt][2] * invl, accO[s][dt][3] * invl);
      int d = dt * 16 + g * 4;
      *(u32x2*)(sOw + (((s * 16 + l15) * 128 + d) ^ pxr)) = pr;
    }
  }
#pragma unroll
  for (int p = 0; p < 8; ++p) {
    int idx = p * 64 + lane;
    int q = idx >> 4, c = idx & 15;
    int j = c ^ (q & 7);
    u32x4 v = *(const u32x4*)(sOw + q * 128 + j * 8);
    *(u32x4*)(o + (size_t)(b * S_LEN + q0 + w * 32 + q) * DM + h * 128 + c * 8) = v;
  }
}

// ---------------- launch ----------------
extern "C" void kernel_launch(void* const* d_in, const int* in_sizes, int n_in,
                              void* d_out, int out_size, void* d_ws, size_t ws_size,
                              hipStream_t stream) {
  const float* x  = (const float*)d_in[0];
  const float* fc = (const float*)d_in[1];
  const float* fs = (const float*)d_in[2];
  const float* wq = (const float*)d_in[4];
  const float* wk = (const float*)d_in[5];
  const float* wv = (const float*)d_in[6];
  const float* wo = (const float*)d_in[7];
  float* out = (float*)d_out;
  char* ws = (char*)d_ws;

  u16* xb  = (u16*)(ws);                 // x bf16      25,165,824
  u16* wqb = (u16*)(ws + 25165824);      // wq bf16     18,874,368 ┐ contiguous = Wcat
  u16* att = (u16*)(ws + 25165824);      // attn out (aliases wq/wk after death)
  u16* wkb = (u16*)(ws + 44040192);      // wk bf16      6,291,456 │ (5120 x 3072)
  u16* wvb = (u16*)(ws + 50331648);      // wv bf16      6,291,456 ┘
  u16* xqb = (u16*)(ws + 56623104);      // xq bf16     25,165,824
  u16* xkb = (u16*)(ws + 81788928);      // xk bf16      8,388,608
  u16* xvT = (u16*)(ws + 90177536);      // V^T bf16     8,388,608
  u16* wob = (u16*)(ws);                 // wo bf16 (aliases xb, dead after gemm_qkv)

  cvt4_kernel<<<13824, 256, 0, stream>>>(x, xb, wq, wqb, wk, wkb, wv, wvb);

  gemm_qkv<<<256, 512, 0, stream>>>(xb, wqb, xqb, xkb, xvT, 3072);

  rope_kernel<<<1024, 256, 0, stream>>>(xkb, fc, fs, NKV, 4096 * NKV * 8);  // K only

  attn_kernel<<<5376, 256, 0, stream>>>(xqb, xkb, xvT, fc, fs, att, wo, wob);

  gemm192_f32<<<dim3(16, 16), 512, 0, stream>>>(att, wob, out, 3072, 3072);
}